// Round 18
// baseline (671.870 us; speedup 1.0000x reference)
//
#include <hip/hip_runtime.h>
#include <hip/hip_fp16.h>
#include <cstdint>

#define GRAPHS 128

using half8 = __attribute__((ext_vector_type(8))) _Float16;
using f32x4 = __attribute__((ext_vector_type(4))) float;

__device__ __forceinline__ int lane_bcast_i(int v, int l) {
  return __builtin_amdgcn_readlane(v, l);
}
__device__ __forceinline__ float lane_bcast_f(float v, int l) {
  return __int_as_float(__builtin_amdgcn_readlane(__float_as_int(v), l));
}
__device__ __forceinline__ void load_lds16(const __half* g, __half* l) {
  __builtin_amdgcn_global_load_lds(
      (const __attribute__((address_space(1))) void*)g,
      (__attribute__((address_space(3))) void*)l, 16, 0, 0);
}
#define WAIT_VM0 __builtin_amdgcn_s_waitcnt(0x0F70)  // vmcnt(0) only

// ---------------- edge prep: degree -> scan -> scatter (CSR by dst, + dstarr) ----------------

__global__ __launch_bounds__(256) void k_deg(const int* __restrict__ ei, int E, int ET,
                                             int* __restrict__ deg) {
  int e = blockIdx.x * 256 + threadIdx.x;
  if (e >= ET) return;
  int d = (e < E) ? ei[E + e] : (e - E);
  atomicAdd(&deg[d], 1);
}

__global__ __launch_bounds__(256) void k_s1(const int* __restrict__ deg, int N,
                                            int* __restrict__ bsum) {
  int b = blockIdx.x, tid = threadIdx.x;
  int i0 = b * 1024 + tid * 4;
  int s = 0;
#pragma unroll
  for (int e = 0; e < 4; ++e) { int i = i0 + e; if (i < N) s += deg[i]; }
#pragma unroll
  for (int o = 32; o; o >>= 1) s += __shfl_xor(s, o);
  __shared__ int wt[4];
  int lane = tid & 63, wid = tid >> 6;
  if (lane == 0) wt[wid] = s;
  __syncthreads();
  if (tid == 0) bsum[b] = wt[0] + wt[1] + wt[2] + wt[3];
}

__global__ void k_s2(int* bsum, int nb) {
  if (threadIdx.x == 0) {
    int run = 0;
    for (int i = 0; i < nb; ++i) { int t = bsum[i]; bsum[i] = run; run += t; }
  }
}

__global__ __launch_bounds__(256) void k_s3(int* __restrict__ deg_cursor,
                                            const int* __restrict__ bsum,
                                            int* __restrict__ rowptr, int N) {
  int b = blockIdx.x, tid = threadIdx.x;
  int lane = tid & 63, wid = tid >> 6;
  int i0 = b * 1024 + tid * 4;
  int d[4];
#pragma unroll
  for (int e = 0; e < 4; ++e) { int i = i0 + e; d[e] = (i < N) ? deg_cursor[i] : 0; }
  int p0 = d[0], p1 = p0 + d[1], p2 = p1 + d[2], p3 = p2 + d[3];
  int incl = p3;
#pragma unroll
  for (int o = 1; o < 64; o <<= 1) { int u = __shfl_up(incl, o); if (lane >= o) incl += u; }
  __shared__ int wt[4];
  if (lane == 63) wt[wid] = incl;
  __syncthreads();
  int woff = 0;
  for (int w = 0; w < wid; ++w) woff += wt[w];
  int ex = bsum[b] + woff + incl - p3;
  int pre[4] = {0, p0, p1, p2};
#pragma unroll
  for (int e = 0; e < 4; ++e) {
    int i = i0 + e;
    if (i < N) { int st = ex + pre[e]; deg_cursor[i] = st; rowptr[i + 1] = st + d[e]; }
  }
  if (b == 0 && tid == 0) rowptr[0] = 0;
}

__global__ __launch_bounds__(256) void k_scatter(const int* __restrict__ ei, int E, int ET,
                                                 int* __restrict__ cursor,
                                                 int* __restrict__ csrs,
                                                 int* __restrict__ dstarr) {
  int e = blockIdx.x * 256 + threadIdx.x;
  if (e >= ET) return;
  int s, d;
  if (e < E) { s = ei[e]; d = ei[E + e]; } else { s = d = e - E; }
  int pos = atomicAdd(&cursor[d], 1);
  csrs[pos] = s;
  dstarr[pos] = d;
}

// ---------------- merged fp16 conversion + weight transpose ----------------

__global__ __launch_bounds__(256) void k_cvtall(
    const float* __restrict__ x, __half* __restrict__ xh,
    const float* __restrict__ W1, __half* __restrict__ w1t,
    const float* __restrict__ W2, __half* __restrict__ w2t,
    int n4, int F, int HC, int LH) {
  int id = blockIdx.x * 256 + threadIdx.x;
  if (id < n4) {
    float4 v = *(const float4*)&x[(size_t)id * 4];
    *(__half2*)&xh[(size_t)id * 4] = __floats2half2_rn(v.x, v.y);
    *(__half2*)&xh[(size_t)id * 4 + 2] = __floats2half2_rn(v.z, v.w);
    return;
  }
  id -= n4;
  if (id < F * HC) {
    int nn = id / F, kk = id % F;
    w1t[(size_t)nn * F + kk] = __float2half(W1[(size_t)kk * HC + nn]);
    return;
  }
  id -= F * HC;
  if (id < HC * LH) {
    int nn = id / HC, kk = id % HC;
    w2t[(size_t)nn * HC + kk] = __float2half(W2[(size_t)kk * LH + nn]);
  }
}

// ---------------- MFMA GEMM, LDS-tiled (verified R14/R15) ----------------

template <int KT, int ASTR>
__global__ __launch_bounds__(256) void k_gemm_mfma(
    const __half* __restrict__ Ah, const __half* __restrict__ Bth,
    __half* __restrict__ C, const float* __restrict__ attS, const float* __restrict__ attD,
    float* __restrict__ aS, float* __restrict__ aD, int M, int NC) {
  constexpr int K8 = KT / 8;
  constexpr int KS = KT / 32;
  __shared__ __align__(16) _Float16 Asm[64 * KT];
  __shared__ float sS[64][4], sD[64][4];
  int tid = threadIdx.x;
  int w = tid >> 6, lane = tid & 63;
  int col = lane & 15, quad = lane >> 4;
  int m0 = blockIdx.x * 64;
  int nblk = blockIdx.y * 64;
  int head = blockIdx.y;
  const half8* A8 = (const half8*)Ah;
  half8* As8 = (half8*)Asm;
  for (int i = tid; i < 64 * K8; i += 256) {
    int row = i / K8, c8 = i % K8;
    int gm = min(m0 + row, M - 1);
    As8[i] = A8[(size_t)gm * K8 + c8];
  }
  __syncthreads();
  int n0w = nblk + w * 16;
  const half8* B8 = (const half8*)Bth;
  half8 bf[KS];
#pragma unroll
  for (int s = 0; s < KS; ++s) bf[s] = B8[(size_t)(n0w + col) * K8 + s * 4 + quad];
  float asv = attS[n0w + col], adv = attD[n0w + col];
  f32x4 accs[4];
#pragma unroll
  for (int i = 0; i < 4; ++i) {
    f32x4 acc = {0.f, 0.f, 0.f, 0.f};
#pragma unroll
    for (int s = 0; s < KS; ++s) {
      half8 a = *(const half8*)&Asm[(i * 16 + col) * KT + s * 32 + quad * 8];
      acc = __builtin_amdgcn_mfma_f32_16x16x32_f16(a, bf[s], acc, 0, 0, 0);
    }
    accs[i] = acc;
#pragma unroll
    for (int r = 0; r < 4; ++r) {
      float sv = acc[r] * asv, dv = acc[r] * adv;
#pragma unroll
      for (int o = 1; o < 16; o <<= 1) { sv += __shfl_xor(sv, o); dv += __shfl_xor(dv, o); }
      if (col == 0) {
        int ml = i * 16 + quad * 4 + r;
        sS[ml][w] = sv; sD[ml][w] = dv;
      }
    }
  }
  __syncthreads();
  if (tid < 64) {
    int m = m0 + tid;
    if (m < M) {
      aS[(size_t)m * ASTR + head] = sS[tid][0] + sS[tid][1] + sS[tid][2] + sS[tid][3];
      aD[(size_t)m * ASTR + head] = sD[tid][0] + sD[tid][1] + sD[tid][2] + sD[tid][3];
    }
  }
  _Float16* Cs = Asm;
#pragma unroll
  for (int i = 0; i < 4; ++i)
#pragma unroll
    for (int r = 0; r < 4; ++r)
      Cs[(i * 16 + quad * 4 + r) * 64 + w * 16 + col] = (_Float16)accs[i][r];
  __syncthreads();
  for (int i = tid; i < 64 * 8; i += 256) {
    int row = i >> 3, c8 = i & 7;
    int gm = m0 + row;
    if (gm < M)
      *(half8*)&C[(size_t)gm * NC + nblk + c8 * 8] = ((half8*)Cs)[row * 8 + c8];
  }
}

// ---------------- per-edge softmax coefs (wave-per-dst), planar [head][dst-pos] -------------

template <int NH>
__global__ __launch_bounds__(256) void k_coef(
    const int* __restrict__ rowptr, const int* __restrict__ csrs,
    const float* __restrict__ aS, const float* __restrict__ aD,
    float* __restrict__ coef, int N, int ETp) {
  constexpr int ASTR = (NH == 3) ? 4 : 1;
  int wv = (blockIdx.x * 256 + (int)threadIdx.x) >> 6;
  if (wv >= N) return;
  int lane = threadIdx.x & 63;
  int start = rowptr[wv], end = rowptr[wv + 1];
  float ad[NH], m[NH], s[NH];
#pragma unroll
  for (int h = 0; h < NH; ++h) { ad[h] = aD[(size_t)wv * ASTR + h]; m[h] = -1e30f; s[h] = 0.f; }
  for (int j = start + lane; j < end; j += 64) {
    int sb = csrs[j];
    float av[NH];
    if (NH == 3) {
      float4 a4 = *(const float4*)&aS[(size_t)sb * 4];
      av[0] = a4.x; av[1] = a4.y; av[2] = a4.z;
    } else {
      av[0] = aS[sb];
    }
#pragma unroll
    for (int h = 0; h < NH; ++h) {
      float v = av[h] + ad[h];
      v = v > 0.f ? v : 0.2f * v;
      float M = fmaxf(m[h], v);
      s[h] = s[h] * __expf(m[h] - M) + __expf(v - M);
      m[h] = M;
    }
  }
#pragma unroll
  for (int h = 0; h < NH; ++h) {
    float mm = m[h], ss = s[h];
#pragma unroll
    for (int o = 1; o < 64; o <<= 1) {
      float om = __shfl_xor(mm, o), os = __shfl_xor(ss, o);
      float M = fmaxf(mm, om);
      ss = ss * __expf(mm - M) + os * __expf(om - M);
      mm = M;
    }
    m[h] = mm;
    s[h] = 1.0f / fmaxf(ss, 1e-16f);
  }
  for (int j = start + lane; j < end; j += 64) {
    int sb = csrs[j];
    float av[NH];
    if (NH == 3) {
      float4 a4 = *(const float4*)&aS[(size_t)sb * 4];
      av[0] = a4.x; av[1] = a4.y; av[2] = a4.z;
    } else {
      av[0] = aS[sb];
    }
#pragma unroll
    for (int h = 0; h < NH; ++h) {
      float v = av[h] + ad[h];
      v = v > 0.f ? v : 0.2f * v;
      coef[(size_t)h * ETp + j] = __expf(v - m[h]) * s[h];
    }
  }
}

// ---------------- edge-parallel aggregation: wave = 64 consecutive CSR edges ----------------
// Zero padding, ONE vmcnt wait per wave. 8 wide DMAs stage 64 fp16 rows (128B slices) into
// 8KB LDS PER WAVE (R17 bug: slot was 2KB -> cross-wave corruption; now 4096 halves/wave).

__global__ __launch_bounds__(256) void k_aggE(
    const int* __restrict__ csrs, const int* __restrict__ dstarr,
    const float* __restrict__ coef, const __half* __restrict__ xp,
    float* __restrict__ outf, int ET, int ETp, int rowstr, int ostr) {
  __shared__ __half stage[4][4096];   // 32KB/block: 8 DMAs x 512 halves per wave
  int wv = (blockIdx.x * 256 + (int)threadIdx.x) >> 6;
  int lane = threadIdx.x & 63;
  int wid = (threadIdx.x >> 6) & 3;
  __half* st = stage[wid];
  int head = blockIdx.y;
  int coloff = head * 64;
  int e0 = wv * 64;
  if (e0 >= ET) return;
  int j = e0 + lane;
  int jc = min(j, ET - 1);
  int sreg = csrs[jc];                          // coalesced
  int dstv = dstarr[jc];                        // coalesced
  float dd = (j < ET) ? coef[(size_t)head * ETp + j] : 0.f;  // coalesced
  // stage all 64 rows: 8 DMAs, no result VGPRs
#pragma unroll
  for (int k = 0; k < 8; ++k) {
    int src = __shfl(sreg, k * 8 + (lane >> 3));
    const __half* g = xp + (size_t)src * rowstr + coloff + (lane & 7) * 8;
    load_lds16(g, st + k * 512);                // 8 rows of 64 halves per DMA
  }
  WAIT_VM0;                                     // the only wait in the wave's lifetime
  float acc = 0.f;
  int dcur = lane_bcast_i(dstv, 0);
#pragma unroll 4
  for (int u = 0; u < 64; ++u) {
    float c = lane_bcast_f(dd, u);
    acc = fmaf(c, __half2float(st[(u >> 3) * 512 + (u & 7) * 64 + lane]), acc);
    int dnext = (u < 63) ? lane_bcast_i(dstv, u + 1) : -1;
    if (dnext != dcur) {                        // wave-uniform branch
      atomicAdd(&outf[(size_t)dcur * ostr + coloff + lane], acc);
      acc = 0.f;
      dcur = dnext;
    }
  }
}

// ---------------- finish layer 1: bias + ELU + fp16 cvt ----------------

__global__ __launch_bounds__(256) void k_fin1(const float* __restrict__ h1f,
                                              const float* __restrict__ b1,
                                              __half* __restrict__ h1h, int n4) {
  int id = blockIdx.x * 256 + threadIdx.x;
  if (id >= n4) return;
  int c = (id % 48) * 4;
  float4 v = *(const float4*)&h1f[(size_t)id * 4];
  float o[4] = {v.x + b1[c], v.y + b1[c + 1], v.z + b1[c + 2], v.w + b1[c + 3]};
#pragma unroll
  for (int k = 0; k < 4; ++k) o[k] = o[k] > 0.f ? o[k] : __expf(o[k]) - 1.f;
  *(__half2*)&h1h[(size_t)id * 4] = __floats2half2_rn(o[0], o[1]);
  *(__half2*)&h1h[(size_t)id * 4 + 2] = __floats2half2_rn(o[2], o[3]);
}

// ---------------- finish layer 2: bias + pool ----------------

__global__ __launch_bounds__(256) void k_fin2(const float* __restrict__ h2f,
                                              const float* __restrict__ b2,
                                              const int* __restrict__ batch,
                                              float* __restrict__ pooled,
                                              float* __restrict__ gcnt, int N) {
  int wv = (blockIdx.x * 256 + (int)threadIdx.x) >> 6;
  int lane = threadIdx.x & 63;
  if (wv >= N) return;
  float v = h2f[(size_t)wv * 64 + lane] + b2[lane];
  int g = batch[wv];
  atomicAdd(&pooled[g * 64 + lane], v);
  if (lane == 0) atomicAdd(&gcnt[g], 1.f);
}

// ---------------- final: mean + linear ----------------

__global__ __launch_bounds__(64) void k_final(const float* __restrict__ pooled,
                                              const float* __restrict__ gcnt,
                                              const float* __restrict__ lw,
                                              const float* __restrict__ lb,
                                              float* __restrict__ out) {
  int g = blockIdx.x, c = threadIdx.x;
  float inv = 1.0f / fmaxf(gcnt[g], 1.0f);
  float pv = pooled[g * 64 + c] * inv;
#pragma unroll
  for (int k = 0; k < 10; ++k) {
    float v = pv * lw[c * 10 + k];
#pragma unroll
    for (int o = 1; o < 64; o <<= 1) v += __shfl_xor(v, o);
    if (c == 0) out[g * 10 + k] = v + lb[k];
  }
}

extern "C" void kernel_launch(void* const* d_in, const int* in_sizes, int n_in,
                              void* d_out, int out_size, void* d_ws, size_t ws_size,
                              hipStream_t stream) {
  const float* x = (const float*)d_in[0];
  const int* ei = (const int*)d_in[1];
  const int* batch = (const int*)d_in[2];
  const float* W1 = (const float*)d_in[3];
  const float* as1 = (const float*)d_in[4];
  const float* ad1 = (const float*)d_in[5];
  const float* b1 = (const float*)d_in[6];
  const float* W2 = (const float*)d_in[7];
  const float* as2 = (const float*)d_in[8];
  const float* ad2 = (const float*)d_in[9];
  const float* b2 = (const float*)d_in[10];
  const float* lw = (const float*)d_in[11];
  const float* lb = (const float*)d_in[12];
  float* out = (float*)d_out;

  const int N = in_sizes[2];        // 50000
  const int E = in_sizes[1] / 2;    // 800000
  const int ET = E + N;             // + self loops
  const int F = in_sizes[0] / N;    // 128
  const int HC = in_sizes[6];       // 192
  const int LH = in_sizes[10];      // 64
  const int ETp = (ET + 255) & ~255;

  size_t off = 0;
  auto alo = [&](size_t bytes) -> char* {
    char* p = (char*)d_ws + off;
    off += (bytes + 255) & ~(size_t)255;
    return p;
  };
  int* cursor = (int*)alo((size_t)N * 4);
  float* pooled = (float*)alo((size_t)GRAPHS * 64 * 4);
  float* gcnt = (float*)alo((size_t)GRAPHS * 4);
  float* h1f = (float*)alo((size_t)N * 192 * 4);    // fp32 edge-flush accumulators
  float* h2f = (float*)alo((size_t)N * 64 * 4);
  size_t zbytes = off;                              // zero everything above
  float* aS1 = (float*)alo((size_t)N * 4 * 4);      // direct-stored by GEMM
  float* aD1 = (float*)alo((size_t)N * 4 * 4);
  float* aS2 = (float*)alo((size_t)N * 4);
  float* aD2 = (float*)alo((size_t)N * 4);
  int* rowptr = (int*)alo(((size_t)N + 1) * 4);
  int* csrs = (int*)alo((size_t)ET * 4);
  int* dstarr = (int*)alo((size_t)ET * 4);
  int* bsum = (int*)alo(64 * 4);
  float* coef = (float*)alo((size_t)3 * ETp * 4);   // planar [head][dst-pos]
  __half* xh = (__half*)alo((size_t)N * F * 2);
  __half* w1t = (__half*)alo((size_t)HC * F * 2);
  __half* w2t = (__half*)alo((size_t)LH * HC * 2);
  __half* xp1 = (__half*)alo((size_t)N * 192 * 2 + 512);
  __half* h1h = (__half*)alo((size_t)N * 192 * 2 + 512);
  __half* xp2 = (__half*)alo((size_t)N * 64 * 2 + 512);

  hipMemsetAsync(d_ws, 0, zbytes, stream);
  int eb = (ET + 255) / 256;
  k_deg<<<eb, 256, 0, stream>>>(ei, E, ET, cursor);
  int nb = (N + 1023) / 1024;
  k_s1<<<nb, 256, 0, stream>>>(cursor, N, bsum);
  k_s2<<<1, 64, 0, stream>>>(bsum, nb);
  k_s3<<<nb, 256, 0, stream>>>(cursor, bsum, rowptr, N);
  k_scatter<<<eb, 256, 0, stream>>>(ei, E, ET, cursor, csrs, dstarr);

  int n4 = (N * F) / 4;
  int cvtTot = n4 + F * HC + HC * LH;
  k_cvtall<<<(cvtTot + 255) / 256, 256, 0, stream>>>(x, xh, W1, w1t, W2, w2t, n4, F, HC, LH);

  int mb = (N + 63) / 64;
  int ab = (N + 3) / 4;
  int ewaves = (ET + 63) / 64;
  int ebk = (ewaves + 3) / 4;

  // ---- layer 1: MFMA GEMM -> coef -> edge-parallel agg (3 planes) -> finish ----
  dim3 gm1(mb, HC / 64);
  k_gemm_mfma<128, 4><<<gm1, 256, 0, stream>>>(xh, w1t, xp1, as1, ad1, aS1, aD1, N, HC);
  k_coef<3><<<ab, 256, 0, stream>>>(rowptr, csrs, aS1, aD1, coef, N, ETp);
  dim3 ge1(ebk, 3);
  k_aggE<<<ge1, 256, 0, stream>>>(csrs, dstarr, coef, xp1, h1f, ET, ETp, 192, 192);
  int f4 = (N * 192) / 4;
  k_fin1<<<(f4 + 255) / 256, 256, 0, stream>>>(h1f, b1, h1h, f4);
  // ---- layer 2: MFMA GEMM -> coef -> edge-parallel agg -> pool ----
  dim3 gm2(mb, LH / 64);
  k_gemm_mfma<192, 1><<<gm2, 256, 0, stream>>>(h1h, w2t, xp2, as2, ad2, aS2, aD2, N, LH);
  k_coef<1><<<ab, 256, 0, stream>>>(rowptr, csrs, aS2, aD2, coef, N, ETp);
  dim3 ge2(ebk, 1);
  k_aggE<<<ge2, 256, 0, stream>>>(csrs, dstarr, coef, xp2, h2f, ET, ETp, 64, 64);
  k_fin2<<<ab, 256, 0, stream>>>(h2f, b2, batch, pooled, gcnt, N);
  k_final<<<GRAPHS, 64, 0, stream>>>(pooled, gcnt, lw, lb, out);
}

// Round 19
// 426.398 us; speedup vs baseline: 1.5757x; 1.5757x over previous
//
#include <hip/hip_runtime.h>
#include <hip/hip_fp16.h>
#include <cstdint>

#define GRAPHS 128

using half8 = __attribute__((ext_vector_type(8))) _Float16;
using f32x4 = __attribute__((ext_vector_type(4))) float;

__device__ __forceinline__ int lane_bcast_i(int v, int l) {
  return __builtin_amdgcn_readlane(v, l);
}
__device__ __forceinline__ float lane_bcast_f(float v, int l) {
  return __int_as_float(__builtin_amdgcn_readlane(__float_as_int(v), l));
}
__device__ __forceinline__ void load_lds16(const __half* g, __half* l) {
  __builtin_amdgcn_global_load_lds(
      (const __attribute__((address_space(1))) void*)g,
      (__attribute__((address_space(3))) void*)l, 16, 0, 0);
}
#define WAIT_VM0 __builtin_amdgcn_s_waitcnt(0x0F70)  // vmcnt(0) only

// ---------------- edge prep: degree -> scan -> scatter (CSR by dst, + dstarr) ----------------

__global__ __launch_bounds__(256) void k_deg(const int* __restrict__ ei, int E, int ET,
                                             int* __restrict__ deg) {
  int e = blockIdx.x * 256 + threadIdx.x;
  if (e >= ET) return;
  int d = (e < E) ? ei[E + e] : (e - E);
  atomicAdd(&deg[d], 1);
}

__global__ __launch_bounds__(256) void k_s1(const int* __restrict__ deg, int N,
                                            int* __restrict__ bsum) {
  int b = blockIdx.x, tid = threadIdx.x;
  int i0 = b * 1024 + tid * 4;
  int s = 0;
#pragma unroll
  for (int e = 0; e < 4; ++e) { int i = i0 + e; if (i < N) s += deg[i]; }
#pragma unroll
  for (int o = 32; o; o >>= 1) s += __shfl_xor(s, o);
  __shared__ int wt[4];
  int lane = tid & 63, wid = tid >> 6;
  if (lane == 0) wt[wid] = s;
  __syncthreads();
  if (tid == 0) bsum[b] = wt[0] + wt[1] + wt[2] + wt[3];
}

__global__ void k_s2(int* bsum, int nb) {
  if (threadIdx.x == 0) {
    int run = 0;
    for (int i = 0; i < nb; ++i) { int t = bsum[i]; bsum[i] = run; run += t; }
  }
}

__global__ __launch_bounds__(256) void k_s3(int* __restrict__ deg_cursor,
                                            const int* __restrict__ bsum,
                                            int* __restrict__ rowptr, int N) {
  int b = blockIdx.x, tid = threadIdx.x;
  int lane = tid & 63, wid = tid >> 6;
  int i0 = b * 1024 + tid * 4;
  int d[4];
#pragma unroll
  for (int e = 0; e < 4; ++e) { int i = i0 + e; d[e] = (i < N) ? deg_cursor[i] : 0; }
  int p0 = d[0], p1 = p0 + d[1], p2 = p1 + d[2], p3 = p2 + d[3];
  int incl = p3;
#pragma unroll
  for (int o = 1; o < 64; o <<= 1) { int u = __shfl_up(incl, o); if (lane >= o) incl += u; }
  __shared__ int wt[4];
  if (lane == 63) wt[wid] = incl;
  __syncthreads();
  int woff = 0;
  for (int w = 0; w < wid; ++w) woff += wt[w];
  int ex = bsum[b] + woff + incl - p3;
  int pre[4] = {0, p0, p1, p2};
#pragma unroll
  for (int e = 0; e < 4; ++e) {
    int i = i0 + e;
    if (i < N) { int st = ex + pre[e]; deg_cursor[i] = st; rowptr[i + 1] = st + d[e]; }
  }
  if (b == 0 && tid == 0) rowptr[0] = 0;
}

__global__ __launch_bounds__(256) void k_scatter(const int* __restrict__ ei, int E, int ET,
                                                 int* __restrict__ cursor,
                                                 int* __restrict__ csrs,
                                                 int* __restrict__ dstarr) {
  int e = blockIdx.x * 256 + threadIdx.x;
  if (e >= ET) return;
  int s, d;
  if (e < E) { s = ei[e]; d = ei[E + e]; } else { s = d = e - E; }
  int pos = atomicAdd(&cursor[d], 1);
  csrs[pos] = s;
  dstarr[pos] = d;
}

// ---------------- merged fp16 conversion + weight transpose ----------------

__global__ __launch_bounds__(256) void k_cvtall(
    const float* __restrict__ x, __half* __restrict__ xh,
    const float* __restrict__ W1, __half* __restrict__ w1t,
    const float* __restrict__ W2, __half* __restrict__ w2t,
    int n4, int F, int HC, int LH) {
  int id = blockIdx.x * 256 + threadIdx.x;
  if (id < n4) {
    float4 v = *(const float4*)&x[(size_t)id * 4];
    *(__half2*)&xh[(size_t)id * 4] = __floats2half2_rn(v.x, v.y);
    *(__half2*)&xh[(size_t)id * 4 + 2] = __floats2half2_rn(v.z, v.w);
    return;
  }
  id -= n4;
  if (id < F * HC) {
    int nn = id / F, kk = id % F;
    w1t[(size_t)nn * F + kk] = __float2half(W1[(size_t)kk * HC + nn]);
    return;
  }
  id -= F * HC;
  if (id < HC * LH) {
    int nn = id / HC, kk = id % HC;
    w2t[(size_t)nn * HC + kk] = __float2half(W2[(size_t)kk * LH + nn]);
  }
}

// ---------------- MFMA GEMM, LDS-tiled (verified R14/R15) ----------------

template <int KT, int ASTR>
__global__ __launch_bounds__(256) void k_gemm_mfma(
    const __half* __restrict__ Ah, const __half* __restrict__ Bth,
    __half* __restrict__ C, const float* __restrict__ attS, const float* __restrict__ attD,
    float* __restrict__ aS, float* __restrict__ aD, int M, int NC) {
  constexpr int K8 = KT / 8;
  constexpr int KS = KT / 32;
  __shared__ __align__(16) _Float16 Asm[64 * KT];
  __shared__ float sS[64][4], sD[64][4];
  int tid = threadIdx.x;
  int w = tid >> 6, lane = tid & 63;
  int col = lane & 15, quad = lane >> 4;
  int m0 = blockIdx.x * 64;
  int nblk = blockIdx.y * 64;
  int head = blockIdx.y;
  const half8* A8 = (const half8*)Ah;
  half8* As8 = (half8*)Asm;
  for (int i = tid; i < 64 * K8; i += 256) {
    int row = i / K8, c8 = i % K8;
    int gm = min(m0 + row, M - 1);
    As8[i] = A8[(size_t)gm * K8 + c8];
  }
  __syncthreads();
  int n0w = nblk + w * 16;
  const half8* B8 = (const half8*)Bth;
  half8 bf[KS];
#pragma unroll
  for (int s = 0; s < KS; ++s) bf[s] = B8[(size_t)(n0w + col) * K8 + s * 4 + quad];
  float asv = attS[n0w + col], adv = attD[n0w + col];
  f32x4 accs[4];
#pragma unroll
  for (int i = 0; i < 4; ++i) {
    f32x4 acc = {0.f, 0.f, 0.f, 0.f};
#pragma unroll
    for (int s = 0; s < KS; ++s) {
      half8 a = *(const half8*)&Asm[(i * 16 + col) * KT + s * 32 + quad * 8];
      acc = __builtin_amdgcn_mfma_f32_16x16x32_f16(a, bf[s], acc, 0, 0, 0);
    }
    accs[i] = acc;
#pragma unroll
    for (int r = 0; r < 4; ++r) {
      float sv = acc[r] * asv, dv = acc[r] * adv;
#pragma unroll
      for (int o = 1; o < 16; o <<= 1) { sv += __shfl_xor(sv, o); dv += __shfl_xor(dv, o); }
      if (col == 0) {
        int ml = i * 16 + quad * 4 + r;
        sS[ml][w] = sv; sD[ml][w] = dv;
      }
    }
  }
  __syncthreads();
  if (tid < 64) {
    int m = m0 + tid;
    if (m < M) {
      aS[(size_t)m * ASTR + head] = sS[tid][0] + sS[tid][1] + sS[tid][2] + sS[tid][3];
      aD[(size_t)m * ASTR + head] = sD[tid][0] + sD[tid][1] + sD[tid][2] + sD[tid][3];
    }
  }
  _Float16* Cs = Asm;
#pragma unroll
  for (int i = 0; i < 4; ++i)
#pragma unroll
    for (int r = 0; r < 4; ++r)
      Cs[(i * 16 + quad * 4 + r) * 64 + w * 16 + col] = (_Float16)accs[i][r];
  __syncthreads();
  for (int i = tid; i < 64 * 8; i += 256) {
    int row = i >> 3, c8 = i & 7;
    int gm = m0 + row;
    if (gm < M)
      *(half8*)&C[(size_t)gm * NC + nblk + c8 * 8] = ((half8*)Cs)[row * 8 + c8];
  }
}

// ---------------- per-edge softmax coefs (wave-per-dst), planar [head][dst-pos] -------------

template <int NH>
__global__ __launch_bounds__(256) void k_coef(
    const int* __restrict__ rowptr, const int* __restrict__ csrs,
    const float* __restrict__ aS, const float* __restrict__ aD,
    float* __restrict__ coef, int N, int ETp) {
  constexpr int ASTR = (NH == 3) ? 4 : 1;
  int wv = (blockIdx.x * 256 + (int)threadIdx.x) >> 6;
  if (wv >= N) return;
  int lane = threadIdx.x & 63;
  int start = rowptr[wv], end = rowptr[wv + 1];
  float ad[NH], m[NH], s[NH];
#pragma unroll
  for (int h = 0; h < NH; ++h) { ad[h] = aD[(size_t)wv * ASTR + h]; m[h] = -1e30f; s[h] = 0.f; }
  for (int j = start + lane; j < end; j += 64) {
    int sb = csrs[j];
    float av[NH];
    if (NH == 3) {
      float4 a4 = *(const float4*)&aS[(size_t)sb * 4];
      av[0] = a4.x; av[1] = a4.y; av[2] = a4.z;
    } else {
      av[0] = aS[sb];
    }
#pragma unroll
    for (int h = 0; h < NH; ++h) {
      float v = av[h] + ad[h];
      v = v > 0.f ? v : 0.2f * v;
      float M = fmaxf(m[h], v);
      s[h] = s[h] * __expf(m[h] - M) + __expf(v - M);
      m[h] = M;
    }
  }
#pragma unroll
  for (int h = 0; h < NH; ++h) {
    float mm = m[h], ss = s[h];
#pragma unroll
    for (int o = 1; o < 64; o <<= 1) {
      float om = __shfl_xor(mm, o), os = __shfl_xor(ss, o);
      float M = fmaxf(mm, om);
      ss = ss * __expf(mm - M) + os * __expf(om - M);
      mm = M;
    }
    m[h] = mm;
    s[h] = 1.0f / fmaxf(ss, 1e-16f);
  }
  for (int j = start + lane; j < end; j += 64) {
    int sb = csrs[j];
    float av[NH];
    if (NH == 3) {
      float4 a4 = *(const float4*)&aS[(size_t)sb * 4];
      av[0] = a4.x; av[1] = a4.y; av[2] = a4.z;
    } else {
      av[0] = aS[sb];
    }
#pragma unroll
    for (int h = 0; h < NH; ++h) {
      float v = av[h] + ad[h];
      v = v > 0.f ? v : 0.2f * v;
      coef[(size_t)h * ETp + j] = __expf(v - m[h]) * s[h];
    }
  }
}

// ---------------- edge-parallel aggregation: wave = 64 consecutive CSR edges ----------------
// Zero padding, ONE vmcnt wait per wave; 8KB LDS staging per wave (32KB/block).

__global__ __launch_bounds__(256) void k_aggE(
    const int* __restrict__ csrs, const int* __restrict__ dstarr,
    const float* __restrict__ coef, const __half* __restrict__ xp,
    float* __restrict__ outf, int ET, int ETp, int rowstr, int ostr) {
  __shared__ __half stage[4][4096];
  int wv = (blockIdx.x * 256 + (int)threadIdx.x) >> 6;
  int lane = threadIdx.x & 63;
  int wid = (threadIdx.x >> 6) & 3;
  __half* st = stage[wid];
  int head = blockIdx.y;
  int coloff = head * 64;
  int e0 = wv * 64;
  if (e0 >= ET) return;
  int j = e0 + lane;
  int jc = min(j, ET - 1);
  int sreg = csrs[jc];                          // coalesced
  int dstv = dstarr[jc];                        // coalesced
  float dd = (j < ET) ? coef[(size_t)head * ETp + j] : 0.f;  // coalesced
#pragma unroll
  for (int k = 0; k < 8; ++k) {
    int src = __shfl(sreg, k * 8 + (lane >> 3));
    const __half* g = xp + (size_t)src * rowstr + coloff + (lane & 7) * 8;
    load_lds16(g, st + k * 512);                // 8 rows of 64 halves per DMA
  }
  WAIT_VM0;                                     // the only wait in the wave's lifetime
  float acc = 0.f;
  int dcur = lane_bcast_i(dstv, 0);
#pragma unroll 4
  for (int u = 0; u < 64; ++u) {
    float c = lane_bcast_f(dd, u);
    acc = fmaf(c, __half2float(st[(u >> 3) * 512 + (u & 7) * 64 + lane]), acc);
    int dnext = (u < 63) ? lane_bcast_i(dstv, u + 1) : -1;
    if (dnext != dcur) {                        // wave-uniform branch
      atomicAdd(&outf[(size_t)dcur * ostr + coloff + lane], acc);
      acc = 0.f;
      dcur = dnext;
    }
  }
}

// ---------------- finish layer 1: bias + ELU + fp16 cvt ----------------

__global__ __launch_bounds__(256) void k_fin1(const float* __restrict__ h1f,
                                              const float* __restrict__ b1,
                                              __half* __restrict__ h1h, int n4) {
  int id = blockIdx.x * 256 + threadIdx.x;
  if (id >= n4) return;
  int c = (id % 48) * 4;
  float4 v = *(const float4*)&h1f[(size_t)id * 4];
  float o[4] = {v.x + b1[c], v.y + b1[c + 1], v.z + b1[c + 2], v.w + b1[c + 3]};
#pragma unroll
  for (int k = 0; k < 4; ++k) o[k] = o[k] > 0.f ? o[k] : __expf(o[k]) - 1.f;
  *(__half2*)&h1h[(size_t)id * 4] = __floats2half2_rn(o[0], o[1]);
  *(__half2*)&h1h[(size_t)id * 4 + 2] = __floats2half2_rn(o[2], o[3]);
}

// ---------------- pooling: one block per graph (batch sorted => contiguous), NO atomics -----

__global__ __launch_bounds__(256) void k_pool(const float* __restrict__ h2f,
                                              const int* __restrict__ batch,
                                              float* __restrict__ pooled,
                                              float* __restrict__ gcnt, int N) {
  int g = blockIdx.x;
  __shared__ int sse[2];
  if (threadIdx.x < 2) {
    int target = g + (int)threadIdx.x;
    int lo = 0, hi = N;
    while (lo < hi) { int mid = (lo + hi) >> 1; if (batch[mid] < target) lo = mid + 1; else hi = mid; }
    sse[threadIdx.x] = lo;
  }
  __syncthreads();
  int start = sse[0], end = sse[1];
  int lane = threadIdx.x & 63, wid = threadIdx.x >> 6;
  float acc = 0.f;
  for (int n = start + wid; n < end; n += 4) acc += h2f[(size_t)n * 64 + lane];
  __shared__ float red[4][64];
  red[wid][lane] = acc;
  __syncthreads();
  if (wid == 0) {
    pooled[g * 64 + lane] = red[0][lane] + red[1][lane] + red[2][lane] + red[3][lane];
    if (lane == 0) gcnt[g] = (float)(end - start);
  }
}

// ---------------- final: mean + bias + linear ----------------

__global__ __launch_bounds__(64) void k_final(const float* __restrict__ pooled,
                                              const float* __restrict__ gcnt,
                                              const float* __restrict__ b2,
                                              const float* __restrict__ lw,
                                              const float* __restrict__ lb,
                                              float* __restrict__ out) {
  int g = blockIdx.x, c = threadIdx.x;
  float inv = 1.0f / fmaxf(gcnt[g], 1.0f);
  float pv = pooled[g * 64 + c] * inv + b2[c];  // bias after mean == mean of (val+bias)
#pragma unroll
  for (int k = 0; k < 10; ++k) {
    float v = pv * lw[c * 10 + k];
#pragma unroll
    for (int o = 1; o < 64; o <<= 1) v += __shfl_xor(v, o);
    if (c == 0) out[g * 10 + k] = v + lb[k];
  }
}

extern "C" void kernel_launch(void* const* d_in, const int* in_sizes, int n_in,
                              void* d_out, int out_size, void* d_ws, size_t ws_size,
                              hipStream_t stream) {
  const float* x = (const float*)d_in[0];
  const int* ei = (const int*)d_in[1];
  const int* batch = (const int*)d_in[2];
  const float* W1 = (const float*)d_in[3];
  const float* as1 = (const float*)d_in[4];
  const float* ad1 = (const float*)d_in[5];
  const float* b1 = (const float*)d_in[6];
  const float* W2 = (const float*)d_in[7];
  const float* as2 = (const float*)d_in[8];
  const float* ad2 = (const float*)d_in[9];
  const float* b2 = (const float*)d_in[10];
  const float* lw = (const float*)d_in[11];
  const float* lb = (const float*)d_in[12];
  float* out = (float*)d_out;

  const int N = in_sizes[2];        // 50000
  const int E = in_sizes[1] / 2;    // 800000
  const int ET = E + N;             // + self loops
  const int F = in_sizes[0] / N;    // 128
  const int HC = in_sizes[6];       // 192
  const int LH = in_sizes[10];      // 64
  const int ETp = (ET + 255) & ~255;

  size_t off = 0;
  auto alo = [&](size_t bytes) -> char* {
    char* p = (char*)d_ws + off;
    off += (bytes + 255) & ~(size_t)255;
    return p;
  };
  int* cursor = (int*)alo((size_t)N * 4);
  float* h1f = (float*)alo((size_t)N * 192 * 4);    // fp32 edge-flush accumulators
  float* h2f = (float*)alo((size_t)N * 64 * 4);
  size_t zbytes = off;                              // zero everything above
  float* pooled = (float*)alo((size_t)GRAPHS * 64 * 4);
  float* gcnt = (float*)alo((size_t)GRAPHS * 4);
  float* aS1 = (float*)alo((size_t)N * 4 * 4);      // direct-stored by GEMM
  float* aD1 = (float*)alo((size_t)N * 4 * 4);
  float* aS2 = (float*)alo((size_t)N * 4);
  float* aD2 = (float*)alo((size_t)N * 4);
  int* rowptr = (int*)alo(((size_t)N + 1) * 4);
  int* csrs = (int*)alo((size_t)ET * 4);
  int* dstarr = (int*)alo((size_t)ET * 4);
  int* bsum = (int*)alo(64 * 4);
  float* coef = (float*)alo((size_t)3 * ETp * 4);   // planar [head][dst-pos]
  __half* xh = (__half*)alo((size_t)N * F * 2);
  __half* w1t = (__half*)alo((size_t)HC * F * 2);
  __half* w2t = (__half*)alo((size_t)LH * HC * 2);
  __half* xp1 = (__half*)alo((size_t)N * 192 * 2 + 512);
  __half* h1h = (__half*)alo((size_t)N * 192 * 2 + 512);
  __half* xp2 = (__half*)alo((size_t)N * 64 * 2 + 512);

  hipMemsetAsync(d_ws, 0, zbytes, stream);
  int eb = (ET + 255) / 256;
  k_deg<<<eb, 256, 0, stream>>>(ei, E, ET, cursor);
  int nb = (N + 1023) / 1024;
  k_s1<<<nb, 256, 0, stream>>>(cursor, N, bsum);
  k_s2<<<1, 64, 0, stream>>>(bsum, nb);
  k_s3<<<nb, 256, 0, stream>>>(cursor, bsum, rowptr, N);
  k_scatter<<<eb, 256, 0, stream>>>(ei, E, ET, cursor, csrs, dstarr);

  int n4 = (N * F) / 4;
  int cvtTot = n4 + F * HC + HC * LH;
  k_cvtall<<<(cvtTot + 255) / 256, 256, 0, stream>>>(x, xh, W1, w1t, W2, w2t, n4, F, HC, LH);

  int mb = (N + 63) / 64;
  int ab = (N + 3) / 4;
  int ewaves = (ET + 63) / 64;
  int ebk = (ewaves + 3) / 4;

  // ---- layer 1: MFMA GEMM -> coef -> edge-parallel agg (3 planes) -> finish ----
  dim3 gm1(mb, HC / 64);
  k_gemm_mfma<128, 4><<<gm1, 256, 0, stream>>>(xh, w1t, xp1, as1, ad1, aS1, aD1, N, HC);
  k_coef<3><<<ab, 256, 0, stream>>>(rowptr, csrs, aS1, aD1, coef, N, ETp);
  dim3 ge1(ebk, 3);
  k_aggE<<<ge1, 256, 0, stream>>>(csrs, dstarr, coef, xp1, h1f, ET, ETp, 192, 192);
  int f4 = (N * 192) / 4;
  k_fin1<<<(f4 + 255) / 256, 256, 0, stream>>>(h1f, b1, h1h, f4);
  // ---- layer 2: MFMA GEMM -> coef -> edge-parallel agg -> pool (atomic-free) ----
  dim3 gm2(mb, LH / 64);
  k_gemm_mfma<192, 1><<<gm2, 256, 0, stream>>>(h1h, w2t, xp2, as2, ad2, aS2, aD2, N, LH);
  k_coef<1><<<ab, 256, 0, stream>>>(rowptr, csrs, aS2, aD2, coef, N, ETp);
  dim3 ge2(ebk, 1);
  k_aggE<<<ge2, 256, 0, stream>>>(csrs, dstarr, coef, xp2, h2f, ET, ETp, 64, 64);
  k_pool<<<GRAPHS, 256, 0, stream>>>(h2f, batch, pooled, gcnt, N);
  k_final<<<GRAPHS, 64, 0, stream>>>(pooled, gcnt, b2, lw, lb, out);
}

// Round 20
// 412.709 us; speedup vs baseline: 1.6279x; 1.0332x over previous
//
#include <hip/hip_runtime.h>
#include <hip/hip_fp16.h>
#include <cstdint>

#define GRAPHS 128

using half8 = __attribute__((ext_vector_type(8))) _Float16;
using f32x4 = __attribute__((ext_vector_type(4))) float;

__device__ __forceinline__ int lane_bcast_i(int v, int l) {
  return __builtin_amdgcn_readlane(v, l);
}
__device__ __forceinline__ float lane_bcast_f(float v, int l) {
  return __int_as_float(__builtin_amdgcn_readlane(__float_as_int(v), l));
}
__device__ __forceinline__ void load_lds16(const __half* g, __half* l) {
  __builtin_amdgcn_global_load_lds(
      (const __attribute__((address_space(1))) void*)g,
      (__attribute__((address_space(3))) void*)l, 16, 0, 0);
}
#define WAIT_VM0 __builtin_amdgcn_s_waitcnt(0x0F70)  // vmcnt(0) only

// ---------------- edge prep: degree -> scan -> scatter (CSR by dst, + dstarr) ----------------

__global__ __launch_bounds__(256) void k_deg(const int* __restrict__ ei, int E, int ET,
                                             int* __restrict__ deg) {
  int e = blockIdx.x * 256 + threadIdx.x;
  if (e >= ET) return;
  int d = (e < E) ? ei[E + e] : (e - E);
  atomicAdd(&deg[d], 1);
}

__global__ __launch_bounds__(256) void k_s1(const int* __restrict__ deg, int N,
                                            int* __restrict__ bsum) {
  int b = blockIdx.x, tid = threadIdx.x;
  int i0 = b * 1024 + tid * 4;
  int s = 0;
#pragma unroll
  for (int e = 0; e < 4; ++e) { int i = i0 + e; if (i < N) s += deg[i]; }
#pragma unroll
  for (int o = 32; o; o >>= 1) s += __shfl_xor(s, o);
  __shared__ int wt[4];
  int lane = tid & 63, wid = tid >> 6;
  if (lane == 0) wt[wid] = s;
  __syncthreads();
  if (tid == 0) bsum[b] = wt[0] + wt[1] + wt[2] + wt[3];
}

__global__ void k_s2(int* bsum, int nb) {
  if (threadIdx.x == 0) {
    int run = 0;
    for (int i = 0; i < nb; ++i) { int t = bsum[i]; bsum[i] = run; run += t; }
  }
}

__global__ __launch_bounds__(256) void k_s3(int* __restrict__ deg_cursor,
                                            const int* __restrict__ bsum,
                                            int* __restrict__ rowptr, int N) {
  int b = blockIdx.x, tid = threadIdx.x;
  int lane = tid & 63, wid = tid >> 6;
  int i0 = b * 1024 + tid * 4;
  int d[4];
#pragma unroll
  for (int e = 0; e < 4; ++e) { int i = i0 + e; d[e] = (i < N) ? deg_cursor[i] : 0; }
  int p0 = d[0], p1 = p0 + d[1], p2 = p1 + d[2], p3 = p2 + d[3];
  int incl = p3;
#pragma unroll
  for (int o = 1; o < 64; o <<= 1) { int u = __shfl_up(incl, o); if (lane >= o) incl += u; }
  __shared__ int wt[4];
  if (lane == 63) wt[wid] = incl;
  __syncthreads();
  int woff = 0;
  for (int w = 0; w < wid; ++w) woff += wt[w];
  int ex = bsum[b] + woff + incl - p3;
  int pre[4] = {0, p0, p1, p2};
#pragma unroll
  for (int e = 0; e < 4; ++e) {
    int i = i0 + e;
    if (i < N) { int st = ex + pre[e]; deg_cursor[i] = st; rowptr[i + 1] = st + d[e]; }
  }
  if (b == 0 && tid == 0) rowptr[0] = 0;
}

__global__ __launch_bounds__(256) void k_scatter(const int* __restrict__ ei, int E, int ET,
                                                 int* __restrict__ cursor,
                                                 int* __restrict__ csrs,
                                                 int* __restrict__ dstarr) {
  int e = blockIdx.x * 256 + threadIdx.x;
  if (e >= ET) return;
  int s, d;
  if (e < E) { s = ei[e]; d = ei[E + e]; } else { s = d = e - E; }
  int pos = atomicAdd(&cursor[d], 1);
  csrs[pos] = s;
  dstarr[pos] = d;
}

// ---------------- merged fp16 conversion + weight transpose ----------------

__global__ __launch_bounds__(256) void k_cvtall(
    const float* __restrict__ x, __half* __restrict__ xh,
    const float* __restrict__ W1, __half* __restrict__ w1t,
    const float* __restrict__ W2, __half* __restrict__ w2t,
    int n4, int F, int HC, int LH) {
  int id = blockIdx.x * 256 + threadIdx.x;
  if (id < n4) {
    float4 v = *(const float4*)&x[(size_t)id * 4];
    *(__half2*)&xh[(size_t)id * 4] = __floats2half2_rn(v.x, v.y);
    *(__half2*)&xh[(size_t)id * 4 + 2] = __floats2half2_rn(v.z, v.w);
    return;
  }
  id -= n4;
  if (id < F * HC) {
    int nn = id / F, kk = id % F;
    w1t[(size_t)nn * F + kk] = __float2half(W1[(size_t)kk * HC + nn]);
    return;
  }
  id -= F * HC;
  if (id < HC * LH) {
    int nn = id / HC, kk = id % HC;
    w2t[(size_t)nn * HC + kk] = __float2half(W2[(size_t)kk * LH + nn]);
  }
}

// ---------------- MFMA GEMM, LDS-tiled (verified R14/R15) ----------------

template <int KT, int ASTR>
__global__ __launch_bounds__(256) void k_gemm_mfma(
    const __half* __restrict__ Ah, const __half* __restrict__ Bth,
    __half* __restrict__ C, const float* __restrict__ attS, const float* __restrict__ attD,
    float* __restrict__ aS, float* __restrict__ aD, int M, int NC) {
  constexpr int K8 = KT / 8;
  constexpr int KS = KT / 32;
  __shared__ __align__(16) _Float16 Asm[64 * KT];
  __shared__ float sS[64][4], sD[64][4];
  int tid = threadIdx.x;
  int w = tid >> 6, lane = tid & 63;
  int col = lane & 15, quad = lane >> 4;
  int m0 = blockIdx.x * 64;
  int nblk = blockIdx.y * 64;
  int head = blockIdx.y;
  const half8* A8 = (const half8*)Ah;
  half8* As8 = (half8*)Asm;
  for (int i = tid; i < 64 * K8; i += 256) {
    int row = i / K8, c8 = i % K8;
    int gm = min(m0 + row, M - 1);
    As8[i] = A8[(size_t)gm * K8 + c8];
  }
  __syncthreads();
  int n0w = nblk + w * 16;
  const half8* B8 = (const half8*)Bth;
  half8 bf[KS];
#pragma unroll
  for (int s = 0; s < KS; ++s) bf[s] = B8[(size_t)(n0w + col) * K8 + s * 4 + quad];
  float asv = attS[n0w + col], adv = attD[n0w + col];
  f32x4 accs[4];
#pragma unroll
  for (int i = 0; i < 4; ++i) {
    f32x4 acc = {0.f, 0.f, 0.f, 0.f};
#pragma unroll
    for (int s = 0; s < KS; ++s) {
      half8 a = *(const half8*)&Asm[(i * 16 + col) * KT + s * 32 + quad * 8];
      acc = __builtin_amdgcn_mfma_f32_16x16x32_f16(a, bf[s], acc, 0, 0, 0);
    }
    accs[i] = acc;
#pragma unroll
    for (int r = 0; r < 4; ++r) {
      float sv = acc[r] * asv, dv = acc[r] * adv;
#pragma unroll
      for (int o = 1; o < 16; o <<= 1) { sv += __shfl_xor(sv, o); dv += __shfl_xor(dv, o); }
      if (col == 0) {
        int ml = i * 16 + quad * 4 + r;
        sS[ml][w] = sv; sD[ml][w] = dv;
      }
    }
  }
  __syncthreads();
  if (tid < 64) {
    int m = m0 + tid;
    if (m < M) {
      aS[(size_t)m * ASTR + head] = sS[tid][0] + sS[tid][1] + sS[tid][2] + sS[tid][3];
      aD[(size_t)m * ASTR + head] = sD[tid][0] + sD[tid][1] + sD[tid][2] + sD[tid][3];
    }
  }
  _Float16* Cs = Asm;
#pragma unroll
  for (int i = 0; i < 4; ++i)
#pragma unroll
    for (int r = 0; r < 4; ++r)
      Cs[(i * 16 + quad * 4 + r) * 64 + w * 16 + col] = (_Float16)accs[i][r];
  __syncthreads();
  for (int i = tid; i < 64 * 8; i += 256) {
    int row = i >> 3, c8 = i & 7;
    int gm = m0 + row;
    if (gm < M)
      *(half8*)&C[(size_t)gm * NC + nblk + c8 * 8] = ((half8*)Cs)[row * 8 + c8];
  }
}

// ---------------- per-edge softmax coefs: aS gathered ONCE (registers cached, deg<=64) ------

template <int NH>
__global__ __launch_bounds__(256) void k_coef(
    const int* __restrict__ rowptr, const int* __restrict__ csrs,
    const float* __restrict__ aS, const float* __restrict__ aD,
    float* __restrict__ coef, int N, int ETp) {
  constexpr int ASTR = (NH == 3) ? 4 : 1;
  int wv = (blockIdx.x * 256 + (int)threadIdx.x) >> 6;
  if (wv >= N) return;
  int lane = threadIdx.x & 63;
  int start = rowptr[wv], end = rowptr[wv + 1];
  float ad[NH], m[NH], s[NH], al[NH];
#pragma unroll
  for (int h = 0; h < NH; ++h) {
    ad[h] = aD[(size_t)wv * ASTR + h];
    m[h] = -1e30f; s[h] = 0.f; al[h] = 0.f;
  }
  int j0 = start + lane;
  bool have = j0 < end;
  if (have) {
    int sb = csrs[j0];
    float av[NH];
    if (NH == 3) {
      float4 a4 = *(const float4*)&aS[(size_t)sb * 4];
      av[0] = a4.x; av[1] = a4.y; av[2] = a4.z;
    } else {
      av[0] = aS[sb];
    }
#pragma unroll
    for (int h = 0; h < NH; ++h) {
      float v = av[h] + ad[h];
      v = v > 0.f ? v : 0.2f * v;
      al[h] = v; m[h] = v; s[h] = 1.f;
    }
  }
  for (int jj = j0 + 64; jj < end; jj += 64) {   // degree > 64 (rare)
    int sb = csrs[jj];
    float av[NH];
    if (NH == 3) {
      float4 a4 = *(const float4*)&aS[(size_t)sb * 4];
      av[0] = a4.x; av[1] = a4.y; av[2] = a4.z;
    } else {
      av[0] = aS[sb];
    }
#pragma unroll
    for (int h = 0; h < NH; ++h) {
      float v = av[h] + ad[h];
      v = v > 0.f ? v : 0.2f * v;
      float M = fmaxf(m[h], v);
      s[h] = s[h] * __expf(m[h] - M) + __expf(v - M);
      m[h] = M;
    }
  }
#pragma unroll
  for (int h = 0; h < NH; ++h) {
    float mm = m[h], ss = s[h];
#pragma unroll
    for (int o = 1; o < 64; o <<= 1) {
      float om = __shfl_xor(mm, o), os = __shfl_xor(ss, o);
      float M = fmaxf(mm, om);
      ss = ss * __expf(mm - M) + os * __expf(om - M);
      mm = M;
    }
    m[h] = mm;
    s[h] = 1.0f / fmaxf(ss, 1e-16f);
  }
  if (have) {   // first 64 edges: reuse registers, no re-gather
#pragma unroll
    for (int h = 0; h < NH; ++h)
      coef[(size_t)h * ETp + j0] = __expf(al[h] - m[h]) * s[h];
  }
  for (int jj = j0 + 64; jj < end; jj += 64) {   // spillover re-gather (rare)
    int sb = csrs[jj];
    float av[NH];
    if (NH == 3) {
      float4 a4 = *(const float4*)&aS[(size_t)sb * 4];
      av[0] = a4.x; av[1] = a4.y; av[2] = a4.z;
    } else {
      av[0] = aS[sb];
    }
#pragma unroll
    for (int h = 0; h < NH; ++h) {
      float v = av[h] + ad[h];
      v = v > 0.f ? v : 0.2f * v;
      coef[(size_t)h * ETp + jj] = __expf(v - m[h]) * s[h];
    }
  }
}

// ---------------- edge-parallel aggregation: wave = 64 consecutive CSR edges ----------------
// ONE vmcnt wait per wave; segment boundaries precomputed as a 64-bit ballot mask (scalar
// bit test per iter instead of readlane+cmp); dcur readlane only at flush points (~4/wave).

__global__ __launch_bounds__(256) void k_aggE(
    const int* __restrict__ csrs, const int* __restrict__ dstarr,
    const float* __restrict__ coef, const __half* __restrict__ xp,
    float* __restrict__ outf, int ET, int ETp, int rowstr, int ostr) {
  __shared__ __half stage[4][4096];
  int wv = (blockIdx.x * 256 + (int)threadIdx.x) >> 6;
  int lane = threadIdx.x & 63;
  int wid = (threadIdx.x >> 6) & 3;
  __half* st = stage[wid];
  int head = blockIdx.y;
  int coloff = head * 64;
  int e0 = wv * 64;
  if (e0 >= ET) return;
  int j = e0 + lane;
  int jc = min(j, ET - 1);
  int sreg = csrs[jc];                          // coalesced
  int dstv = dstarr[jc];                        // coalesced
  float dd = (j < ET) ? coef[(size_t)head * ETp + j] : 0.f;  // coalesced
#pragma unroll
  for (int k = 0; k < 8; ++k) {
    int src = __shfl(sreg, k * 8 + (lane >> 3));
    const __half* g = xp + (size_t)src * rowstr + coloff + (lane & 7) * 8;
    load_lds16(g, st + k * 512);                // 8 rows of 64 halves per DMA
  }
  int dn = __shfl_down(dstv, 1);
  unsigned long long bmask = __ballot(lane == 63 || dn != dstv);  // segment-end lanes
  WAIT_VM0;                                     // the only wait in the wave's lifetime
  float acc = 0.f;
  int dcur = lane_bcast_i(dstv, 0);
#pragma unroll 4
  for (int u = 0; u < 64; ++u) {
    float c = lane_bcast_f(dd, u);
    acc = fmaf(c, __half2float(st[(u >> 3) * 512 + (u & 7) * 64 + lane]), acc);
    if ((bmask >> u) & 1ull) {                  // wave-uniform scalar test
      atomicAdd(&outf[(size_t)dcur * ostr + coloff + lane], acc);
      acc = 0.f;
      if (u < 63) dcur = lane_bcast_i(dstv, u + 1);
    }
  }
}

// ---------------- finish layer 1: bias + ELU + fp16 cvt ----------------

__global__ __launch_bounds__(256) void k_fin1(const float* __restrict__ h1f,
                                              const float* __restrict__ b1,
                                              __half* __restrict__ h1h, int n4) {
  int id = blockIdx.x * 256 + threadIdx.x;
  if (id >= n4) return;
  int c = (id % 48) * 4;
  float4 v = *(const float4*)&h1f[(size_t)id * 4];
  float o[4] = {v.x + b1[c], v.y + b1[c + 1], v.z + b1[c + 2], v.w + b1[c + 3]};
#pragma unroll
  for (int k = 0; k < 4; ++k) o[k] = o[k] > 0.f ? o[k] : __expf(o[k]) - 1.f;
  *(__half2*)&h1h[(size_t)id * 4] = __floats2half2_rn(o[0], o[1]);
  *(__half2*)&h1h[(size_t)id * 4 + 2] = __floats2half2_rn(o[2], o[3]);
}

// ---------------- fused pooling + final linear (one block per graph, NO atomics) ------------

__global__ __launch_bounds__(256) void k_poolfinal(
    const float* __restrict__ h2f, const int* __restrict__ batch,
    const float* __restrict__ b2, const float* __restrict__ lw,
    const float* __restrict__ lb, float* __restrict__ out, int N) {
  int g = blockIdx.x;
  __shared__ int sse[2];
  __shared__ float red[4][64];
  if (threadIdx.x < 2) {
    int target = g + (int)threadIdx.x;
    int lo = 0, hi = N;
    while (lo < hi) { int mid = (lo + hi) >> 1; if (batch[mid] < target) lo = mid + 1; else hi = mid; }
    sse[threadIdx.x] = lo;
  }
  __syncthreads();
  int start = sse[0], end = sse[1];
  int lane = threadIdx.x & 63, wid = threadIdx.x >> 6;
  float acc = 0.f;
  for (int n = start + wid; n < end; n += 4) acc += h2f[(size_t)n * 64 + lane];
  red[wid][lane] = acc;
  __syncthreads();
  if (wid == 0) {
    float inv = 1.0f / fmaxf((float)(end - start), 1.0f);
    float pv = (red[0][lane] + red[1][lane] + red[2][lane] + red[3][lane]) * inv + b2[lane];
#pragma unroll
    for (int k = 0; k < 10; ++k) {
      float v = pv * lw[lane * 10 + k];
#pragma unroll
      for (int o = 1; o < 64; o <<= 1) v += __shfl_xor(v, o);
      if (lane == 0) out[g * 10 + k] = v + lb[k];
    }
  }
}

extern "C" void kernel_launch(void* const* d_in, const int* in_sizes, int n_in,
                              void* d_out, int out_size, void* d_ws, size_t ws_size,
                              hipStream_t stream) {
  const float* x = (const float*)d_in[0];
  const int* ei = (const int*)d_in[1];
  const int* batch = (const int*)d_in[2];
  const float* W1 = (const float*)d_in[3];
  const float* as1 = (const float*)d_in[4];
  const float* ad1 = (const float*)d_in[5];
  const float* b1 = (const float*)d_in[6];
  const float* W2 = (const float*)d_in[7];
  const float* as2 = (const float*)d_in[8];
  const float* ad2 = (const float*)d_in[9];
  const float* b2 = (const float*)d_in[10];
  const float* lw = (const float*)d_in[11];
  const float* lb = (const float*)d_in[12];
  float* out = (float*)d_out;

  const int N = in_sizes[2];        // 50000
  const int E = in_sizes[1] / 2;    // 800000
  const int ET = E + N;             // + self loops
  const int F = in_sizes[0] / N;    // 128
  const int HC = in_sizes[6];       // 192
  const int LH = in_sizes[10];      // 64
  const int ETp = (ET + 255) & ~255;

  size_t off = 0;
  auto alo = [&](size_t bytes) -> char* {
    char* p = (char*)d_ws + off;
    off += (bytes + 255) & ~(size_t)255;
    return p;
  };
  int* cursor = (int*)alo((size_t)N * 4);
  float* h1f = (float*)alo((size_t)N * 192 * 4);    // fp32 edge-flush accumulators
  float* h2f = (float*)alo((size_t)N * 64 * 4);
  size_t zbytes = off;                              // zero everything above
  float* aS1 = (float*)alo((size_t)N * 4 * 4);      // direct-stored by GEMM
  float* aD1 = (float*)alo((size_t)N * 4 * 4);
  float* aS2 = (float*)alo((size_t)N * 4);
  float* aD2 = (float*)alo((size_t)N * 4);
  int* rowptr = (int*)alo(((size_t)N + 1) * 4);
  int* csrs = (int*)alo((size_t)ET * 4);
  int* dstarr = (int*)alo((size_t)ET * 4);
  int* bsum = (int*)alo(64 * 4);
  float* coef = (float*)alo((size_t)3 * ETp * 4);   // planar [head][dst-pos]
  __half* xh = (__half*)alo((size_t)N * F * 2);
  __half* w1t = (__half*)alo((size_t)HC * F * 2);
  __half* w2t = (__half*)alo((size_t)LH * HC * 2);
  __half* xp1 = (__half*)alo((size_t)N * 192 * 2 + 512);
  __half* h1h = (__half*)alo((size_t)N * 192 * 2 + 512);
  __half* xp2 = (__half*)alo((size_t)N * 64 * 2 + 512);

  hipMemsetAsync(d_ws, 0, zbytes, stream);
  int eb = (ET + 255) / 256;
  k_deg<<<eb, 256, 0, stream>>>(ei, E, ET, cursor);
  int nb = (N + 1023) / 1024;
  k_s1<<<nb, 256, 0, stream>>>(cursor, N, bsum);
  k_s2<<<1, 64, 0, stream>>>(bsum, nb);
  k_s3<<<nb, 256, 0, stream>>>(cursor, bsum, rowptr, N);
  k_scatter<<<eb, 256, 0, stream>>>(ei, E, ET, cursor, csrs, dstarr);

  int n4 = (N * F) / 4;
  int cvtTot = n4 + F * HC + HC * LH;
  k_cvtall<<<(cvtTot + 255) / 256, 256, 0, stream>>>(x, xh, W1, w1t, W2, w2t, n4, F, HC, LH);

  int mb = (N + 63) / 64;
  int ab = (N + 3) / 4;
  int ewaves = (ET + 63) / 64;
  int ebk = (ewaves + 3) / 4;

  // ---- layer 1: MFMA GEMM -> coef -> edge-parallel agg (3 planes) -> finish ----
  dim3 gm1(mb, HC / 64);
  k_gemm_mfma<128, 4><<<gm1, 256, 0, stream>>>(xh, w1t, xp1, as1, ad1, aS1, aD1, N, HC);
  k_coef<3><<<ab, 256, 0, stream>>>(rowptr, csrs, aS1, aD1, coef, N, ETp);
  dim3 ge1(ebk, 3);
  k_aggE<<<ge1, 256, 0, stream>>>(csrs, dstarr, coef, xp1, h1f, ET, ETp, 192, 192);
  int f4 = (N * 192) / 4;
  k_fin1<<<(f4 + 255) / 256, 256, 0, stream>>>(h1f, b1, h1h, f4);
  // ---- layer 2: MFMA GEMM -> coef -> edge-parallel agg -> fused pool+final ----
  dim3 gm2(mb, LH / 64);
  k_gemm_mfma<192, 1><<<gm2, 256, 0, stream>>>(h1h, w2t, xp2, as2, ad2, aS2, aD2, N, LH);
  k_coef<1><<<ab, 256, 0, stream>>>(rowptr, csrs, aS2, aD2, coef, N, ETp);
  dim3 ge2(ebk, 1);
  k_aggE<<<ge2, 256, 0, stream>>>(csrs, dstarr, coef, xp2, h2f, ET, ETp, 64, 64);
  k_poolfinal<<<GRAPHS, 256, 0, stream>>>(h2f, batch, b2, lw, lb, out, N);
}

// Round 21
// 407.672 us; speedup vs baseline: 1.6481x; 1.0124x over previous
//
#include <hip/hip_runtime.h>
#include <hip/hip_fp16.h>
#include <cstdint>

#define GRAPHS 128

using half8 = __attribute__((ext_vector_type(8))) _Float16;
using f32x4 = __attribute__((ext_vector_type(4))) float;

__device__ __forceinline__ int lane_bcast_i(int v, int l) {
  return __builtin_amdgcn_readlane(v, l);
}
__device__ __forceinline__ float lane_bcast_f(float v, int l) {
  return __int_as_float(__builtin_amdgcn_readlane(__float_as_int(v), l));
}
__device__ __forceinline__ void load_lds16(const __half* g, __half* l) {
  __builtin_amdgcn_global_load_lds(
      (const __attribute__((address_space(1))) void*)g,
      (__attribute__((address_space(3))) void*)l, 16, 0, 0);
}
#define WAIT_VM0 __builtin_amdgcn_s_waitcnt(0x0F70)  // vmcnt(0) only

// ---------------- edge prep: degree -> scan -> scatter (CSR by dst, + dstarr) ----------------

__global__ __launch_bounds__(256) void k_deg(const int* __restrict__ ei, int E, int ET,
                                             int* __restrict__ deg) {
  int e = blockIdx.x * 256 + threadIdx.x;
  if (e >= ET) return;
  int d = (e < E) ? ei[E + e] : (e - E);
  atomicAdd(&deg[d], 1);
}

__global__ __launch_bounds__(256) void k_s1(const int* __restrict__ deg, int N,
                                            int* __restrict__ bsum) {
  int b = blockIdx.x, tid = threadIdx.x;
  int i0 = b * 1024 + tid * 4;
  int s = 0;
#pragma unroll
  for (int e = 0; e < 4; ++e) { int i = i0 + e; if (i < N) s += deg[i]; }
#pragma unroll
  for (int o = 32; o; o >>= 1) s += __shfl_xor(s, o);
  __shared__ int wt[4];
  int lane = tid & 63, wid = tid >> 6;
  if (lane == 0) wt[wid] = s;
  __syncthreads();
  if (tid == 0) bsum[b] = wt[0] + wt[1] + wt[2] + wt[3];
}

__global__ void k_s2(int* bsum, int nb) {
  if (threadIdx.x == 0) {
    int run = 0;
    for (int i = 0; i < nb; ++i) { int t = bsum[i]; bsum[i] = run; run += t; }
  }
}

__global__ __launch_bounds__(256) void k_s3(int* __restrict__ deg_cursor,
                                            const int* __restrict__ bsum,
                                            int* __restrict__ rowptr, int N) {
  int b = blockIdx.x, tid = threadIdx.x;
  int lane = tid & 63, wid = tid >> 6;
  int i0 = b * 1024 + tid * 4;
  int d[4];
#pragma unroll
  for (int e = 0; e < 4; ++e) { int i = i0 + e; d[e] = (i < N) ? deg_cursor[i] : 0; }
  int p0 = d[0], p1 = p0 + d[1], p2 = p1 + d[2], p3 = p2 + d[3];
  int incl = p3;
#pragma unroll
  for (int o = 1; o < 64; o <<= 1) { int u = __shfl_up(incl, o); if (lane >= o) incl += u; }
  __shared__ int wt[4];
  if (lane == 63) wt[wid] = incl;
  __syncthreads();
  int woff = 0;
  for (int w = 0; w < wid; ++w) woff += wt[w];
  int ex = bsum[b] + woff + incl - p3;
  int pre[4] = {0, p0, p1, p2};
#pragma unroll
  for (int e = 0; e < 4; ++e) {
    int i = i0 + e;
    if (i < N) { int st = ex + pre[e]; deg_cursor[i] = st; rowptr[i + 1] = st + d[e]; }
  }
  if (b == 0 && tid == 0) rowptr[0] = 0;
}

__global__ __launch_bounds__(256) void k_scatter(const int* __restrict__ ei, int E, int ET,
                                                 int* __restrict__ cursor,
                                                 int* __restrict__ csrs,
                                                 int* __restrict__ dstarr) {
  int e = blockIdx.x * 256 + threadIdx.x;
  if (e >= ET) return;
  int s, d;
  if (e < E) { s = ei[e]; d = ei[E + e]; } else { s = d = e - E; }
  int pos = atomicAdd(&cursor[d], 1);
  csrs[pos] = s;
  dstarr[pos] = d;
}

// ---------------- weight transpose + fp16 cvt (small) ----------------

__global__ __launch_bounds__(256) void k_wt(
    const float* __restrict__ W1, __half* __restrict__ w1t,
    const float* __restrict__ W2, __half* __restrict__ w2t, int F, int HC, int LH) {
  int id = blockIdx.x * 256 + threadIdx.x;
  if (id < F * HC) {
    int nn = id / F, kk = id % F;
    w1t[(size_t)nn * F + kk] = __float2half(W1[(size_t)kk * HC + nn]);
    return;
  }
  id -= F * HC;
  if (id < HC * LH) {
    int nn = id / HC, kk = id % HC;
    w2t[(size_t)nn * HC + kk] = __float2half(W2[(size_t)kk * LH + nn]);
  }
}

// ---------------- MFMA GEMM, LDS-tiled, fp32 A staged with inline cvt ----------------
// MODE 0: A = raw fp32 (x).  MODE 1: A = fp32 accumulators + bias + ELU (h1f) — fuses k_fin1.
// Frag maps verified R14/R15 (absmax 3e-5).

template <int KT, int ASTR, int MODE>
__global__ __launch_bounds__(256) void k_gemm_mfma(
    const float* __restrict__ Af, const __half* __restrict__ Bth,
    __half* __restrict__ C, const float* __restrict__ attS, const float* __restrict__ attD,
    float* __restrict__ aS, float* __restrict__ aD, const float* __restrict__ bias,
    int M, int NC) {
  constexpr int K8 = KT / 8;
  constexpr int KS = KT / 32;
  __shared__ __align__(16) _Float16 Asm[64 * KT];
  __shared__ float sS[64][4], sD[64][4];
  int tid = threadIdx.x;
  int w = tid >> 6, lane = tid & 63;
  int col = lane & 15, quad = lane >> 4;
  int m0 = blockIdx.x * 64;
  int nblk = blockIdx.y * 64;
  int head = blockIdx.y;
  half8* As8 = (half8*)Asm;
  for (int i = tid; i < 64 * K8; i += 256) {
    int row = i / K8, c8 = i % K8;
    int gm = min(m0 + row, M - 1);
    const float* src = Af + (size_t)gm * KT + c8 * 8;
    float4 v0 = *(const float4*)src;
    float4 v1 = *(const float4*)(src + 4);
    float o[8] = {v0.x, v0.y, v0.z, v0.w, v1.x, v1.y, v1.z, v1.w};
    if (MODE == 1) {
      int c = c8 * 8;
#pragma unroll
      for (int k = 0; k < 8; ++k) {
        float t = o[k] + bias[c + k];
        o[k] = t > 0.f ? t : __expf(t) - 1.f;
      }
    }
    half8 h;
#pragma unroll
    for (int k = 0; k < 8; ++k) h[k] = (_Float16)o[k];
    As8[i] = h;
  }
  __syncthreads();
  int n0w = nblk + w * 16;
  const half8* B8 = (const half8*)Bth;
  half8 bf[KS];
#pragma unroll
  for (int s = 0; s < KS; ++s) bf[s] = B8[(size_t)(n0w + col) * K8 + s * 4 + quad];
  float asv = attS[n0w + col], adv = attD[n0w + col];
  f32x4 accs[4];
#pragma unroll
  for (int i = 0; i < 4; ++i) {
    f32x4 acc = {0.f, 0.f, 0.f, 0.f};
#pragma unroll
    for (int s = 0; s < KS; ++s) {
      half8 a = *(const half8*)&Asm[(i * 16 + col) * KT + s * 32 + quad * 8];
      acc = __builtin_amdgcn_mfma_f32_16x16x32_f16(a, bf[s], acc, 0, 0, 0);
    }
    accs[i] = acc;
#pragma unroll
    for (int r = 0; r < 4; ++r) {
      float sv = acc[r] * asv, dv = acc[r] * adv;
#pragma unroll
      for (int o = 1; o < 16; o <<= 1) { sv += __shfl_xor(sv, o); dv += __shfl_xor(dv, o); }
      if (col == 0) {
        int ml = i * 16 + quad * 4 + r;
        sS[ml][w] = sv; sD[ml][w] = dv;
      }
    }
  }
  __syncthreads();
  if (tid < 64) {
    int m = m0 + tid;
    if (m < M) {
      aS[(size_t)m * ASTR + head] = sS[tid][0] + sS[tid][1] + sS[tid][2] + sS[tid][3];
      aD[(size_t)m * ASTR + head] = sD[tid][0] + sD[tid][1] + sD[tid][2] + sD[tid][3];
    }
  }
  _Float16* Cs = Asm;
#pragma unroll
  for (int i = 0; i < 4; ++i)
#pragma unroll
    for (int r = 0; r < 4; ++r)
      Cs[(i * 16 + quad * 4 + r) * 64 + w * 16 + col] = (_Float16)accs[i][r];
  __syncthreads();
  for (int i = tid; i < 64 * 8; i += 256) {
    int row = i >> 3, c8 = i & 7;
    int gm = m0 + row;
    if (gm < M)
      *(half8*)&C[(size_t)gm * NC + nblk + c8 * 8] = ((half8*)Cs)[row * 8 + c8];
  }
}

// ---------------- per-edge softmax coefs: aS gathered ONCE (registers cached, deg<=64) ------

template <int NH>
__global__ __launch_bounds__(256) void k_coef(
    const int* __restrict__ rowptr, const int* __restrict__ csrs,
    const float* __restrict__ aS, const float* __restrict__ aD,
    float* __restrict__ coef, int N, int ETp) {
  constexpr int ASTR = (NH == 3) ? 4 : 1;
  int wv = (blockIdx.x * 256 + (int)threadIdx.x) >> 6;
  if (wv >= N) return;
  int lane = threadIdx.x & 63;
  int start = rowptr[wv], end = rowptr[wv + 1];
  float ad[NH], m[NH], s[NH], al[NH];
#pragma unroll
  for (int h = 0; h < NH; ++h) {
    ad[h] = aD[(size_t)wv * ASTR + h];
    m[h] = -1e30f; s[h] = 0.f; al[h] = 0.f;
  }
  int j0 = start + lane;
  bool have = j0 < end;
  if (have) {
    int sb = csrs[j0];
    float av[NH];
    if (NH == 3) {
      float4 a4 = *(const float4*)&aS[(size_t)sb * 4];
      av[0] = a4.x; av[1] = a4.y; av[2] = a4.z;
    } else {
      av[0] = aS[sb];
    }
#pragma unroll
    for (int h = 0; h < NH; ++h) {
      float v = av[h] + ad[h];
      v = v > 0.f ? v : 0.2f * v;
      al[h] = v; m[h] = v; s[h] = 1.f;
    }
  }
  for (int jj = j0 + 64; jj < end; jj += 64) {   // degree > 64 (rare)
    int sb = csrs[jj];
    float av[NH];
    if (NH == 3) {
      float4 a4 = *(const float4*)&aS[(size_t)sb * 4];
      av[0] = a4.x; av[1] = a4.y; av[2] = a4.z;
    } else {
      av[0] = aS[sb];
    }
#pragma unroll
    for (int h = 0; h < NH; ++h) {
      float v = av[h] + ad[h];
      v = v > 0.f ? v : 0.2f * v;
      float M = fmaxf(m[h], v);
      s[h] = s[h] * __expf(m[h] - M) + __expf(v - M);
      m[h] = M;
    }
  }
#pragma unroll
  for (int h = 0; h < NH; ++h) {
    float mm = m[h], ss = s[h];
#pragma unroll
    for (int o = 1; o < 64; o <<= 1) {
      float om = __shfl_xor(mm, o), os = __shfl_xor(ss, o);
      float M = fmaxf(mm, om);
      ss = ss * __expf(mm - M) + os * __expf(om - M);
      mm = M;
    }
    m[h] = mm;
    s[h] = 1.0f / fmaxf(ss, 1e-16f);
  }
  if (have) {   // first 64 edges: reuse registers, no re-gather
#pragma unroll
    for (int h = 0; h < NH; ++h)
      coef[(size_t)h * ETp + j0] = __expf(al[h] - m[h]) * s[h];
  }
  for (int jj = j0 + 64; jj < end; jj += 64) {   // spillover re-gather (rare)
    int sb = csrs[jj];
    float av[NH];
    if (NH == 3) {
      float4 a4 = *(const float4*)&aS[(size_t)sb * 4];
      av[0] = a4.x; av[1] = a4.y; av[2] = a4.z;
    } else {
      av[0] = aS[sb];
    }
#pragma unroll
    for (int h = 0; h < NH; ++h) {
      float v = av[h] + ad[h];
      v = v > 0.f ? v : 0.2f * v;
      coef[(size_t)h * ETp + jj] = __expf(v - m[h]) * s[h];
    }
  }
}

// ---------------- edge-parallel aggregation: wave = 64 consecutive CSR edges ----------------

__global__ __launch_bounds__(256) void k_aggE(
    const int* __restrict__ csrs, const int* __restrict__ dstarr,
    const float* __restrict__ coef, const __half* __restrict__ xp,
    float* __restrict__ outf, int ET, int ETp, int rowstr, int ostr) {
  __shared__ __half stage[4][4096];
  int wv = (blockIdx.x * 256 + (int)threadIdx.x) >> 6;
  int lane = threadIdx.x & 63;
  int wid = (threadIdx.x >> 6) & 3;
  __half* st = stage[wid];
  int head = blockIdx.y;
  int coloff = head * 64;
  int e0 = wv * 64;
  if (e0 >= ET) return;
  int j = e0 + lane;
  int jc = min(j, ET - 1);
  int sreg = csrs[jc];                          // coalesced
  int dstv = dstarr[jc];                        // coalesced
  float dd = (j < ET) ? coef[(size_t)head * ETp + j] : 0.f;  // coalesced
#pragma unroll
  for (int k = 0; k < 8; ++k) {
    int src = __shfl(sreg, k * 8 + (lane >> 3));
    const __half* g = xp + (size_t)src * rowstr + coloff + (lane & 7) * 8;
    load_lds16(g, st + k * 512);                // 8 rows of 64 halves per DMA
  }
  int dn = __shfl_down(dstv, 1);
  unsigned long long bmask = __ballot(lane == 63 || dn != dstv);  // segment-end lanes
  WAIT_VM0;                                     // the only wait in the wave's lifetime
  float acc = 0.f;
  int dcur = lane_bcast_i(dstv, 0);
#pragma unroll 4
  for (int u = 0; u < 64; ++u) {
    float c = lane_bcast_f(dd, u);
    acc = fmaf(c, __half2float(st[(u >> 3) * 512 + (u & 7) * 64 + lane]), acc);
    if ((bmask >> u) & 1ull) {                  // wave-uniform scalar test
      atomicAdd(&outf[(size_t)dcur * ostr + coloff + lane], acc);
      acc = 0.f;
      if (u < 63) dcur = lane_bcast_i(dstv, u + 1);
    }
  }
}

// ---------------- fused pooling + final linear (one block per graph, NO atomics) ------------

__global__ __launch_bounds__(256) void k_poolfinal(
    const float* __restrict__ h2f, const int* __restrict__ batch,
    const float* __restrict__ b2, const float* __restrict__ lw,
    const float* __restrict__ lb, float* __restrict__ out, int N) {
  int g = blockIdx.x;
  __shared__ int sse[2];
  __shared__ float red[4][64];
  if (threadIdx.x < 2) {
    int target = g + (int)threadIdx.x;
    int lo = 0, hi = N;
    while (lo < hi) { int mid = (lo + hi) >> 1; if (batch[mid] < target) lo = mid + 1; else hi = mid; }
    sse[threadIdx.x] = lo;
  }
  __syncthreads();
  int start = sse[0], end = sse[1];
  int lane = threadIdx.x & 63, wid = threadIdx.x >> 6;
  float acc = 0.f;
  for (int n = start + wid; n < end; n += 4) acc += h2f[(size_t)n * 64 + lane];
  red[wid][lane] = acc;
  __syncthreads();
  if (wid == 0) {
    float inv = 1.0f / fmaxf((float)(end - start), 1.0f);
    float pv = (red[0][lane] + red[1][lane] + red[2][lane] + red[3][lane]) * inv + b2[lane];
#pragma unroll
    for (int k = 0; k < 10; ++k) {
      float v = pv * lw[lane * 10 + k];
#pragma unroll
      for (int o = 1; o < 64; o <<= 1) v += __shfl_xor(v, o);
      if (lane == 0) out[g * 10 + k] = v + lb[k];
    }
  }
}

extern "C" void kernel_launch(void* const* d_in, const int* in_sizes, int n_in,
                              void* d_out, int out_size, void* d_ws, size_t ws_size,
                              hipStream_t stream) {
  const float* x = (const float*)d_in[0];
  const int* ei = (const int*)d_in[1];
  const int* batch = (const int*)d_in[2];
  const float* W1 = (const float*)d_in[3];
  const float* as1 = (const float*)d_in[4];
  const float* ad1 = (const float*)d_in[5];
  const float* b1 = (const float*)d_in[6];
  const float* W2 = (const float*)d_in[7];
  const float* as2 = (const float*)d_in[8];
  const float* ad2 = (const float*)d_in[9];
  const float* b2 = (const float*)d_in[10];
  const float* lw = (const float*)d_in[11];
  const float* lb = (const float*)d_in[12];
  float* out = (float*)d_out;

  const int N = in_sizes[2];        // 50000
  const int E = in_sizes[1] / 2;    // 800000
  const int ET = E + N;             // + self loops
  const int F = in_sizes[0] / N;    // 128
  const int HC = in_sizes[6];       // 192
  const int LH = in_sizes[10];      // 64
  const int ETp = (ET + 255) & ~255;

  size_t off = 0;
  auto alo = [&](size_t bytes) -> char* {
    char* p = (char*)d_ws + off;
    off += (bytes + 255) & ~(size_t)255;
    return p;
  };
  int* cursor = (int*)alo((size_t)N * 4);
  float* h1f = (float*)alo((size_t)N * 192 * 4);    // fp32 edge-flush accumulators
  float* h2f = (float*)alo((size_t)N * 64 * 4);
  size_t zbytes = off;                              // zero everything above
  float* aS1 = (float*)alo((size_t)N * 4 * 4);      // direct-stored by GEMM
  float* aD1 = (float*)alo((size_t)N * 4 * 4);
  float* aS2 = (float*)alo((size_t)N * 4);
  float* aD2 = (float*)alo((size_t)N * 4);
  int* rowptr = (int*)alo(((size_t)N + 1) * 4);
  int* csrs = (int*)alo((size_t)ET * 4);
  int* dstarr = (int*)alo((size_t)ET * 4);
  int* bsum = (int*)alo(64 * 4);
  float* coef = (float*)alo((size_t)3 * ETp * 4);   // planar [head][dst-pos]
  __half* w1t = (__half*)alo((size_t)HC * F * 2);
  __half* w2t = (__half*)alo((size_t)LH * HC * 2);
  __half* xp1 = (__half*)alo((size_t)N * 192 * 2 + 512);  // +pad: DMA clamp overreach
  __half* xp2 = (__half*)alo((size_t)N * 64 * 2 + 512);

  hipMemsetAsync(d_ws, 0, zbytes, stream);
  int eb = (ET + 255) / 256;
  k_deg<<<eb, 256, 0, stream>>>(ei, E, ET, cursor);
  int nb = (N + 1023) / 1024;
  k_s1<<<nb, 256, 0, stream>>>(cursor, N, bsum);
  k_s2<<<1, 64, 0, stream>>>(bsum, nb);
  k_s3<<<nb, 256, 0, stream>>>(cursor, bsum, rowptr, N);
  k_scatter<<<eb, 256, 0, stream>>>(ei, E, ET, cursor, csrs, dstarr);

  int wtTot = F * HC + HC * LH;
  k_wt<<<(wtTot + 255) / 256, 256, 0, stream>>>(W1, w1t, W2, w2t, F, HC, LH);

  int mb = (N + 63) / 64;
  int ab = (N + 3) / 4;
  int ewaves = (ET + 63) / 64;
  int ebk = (ewaves + 3) / 4;

  // ---- layer 1: MFMA GEMM (fp32 A inline-cvt) -> coef -> edge-parallel agg (3 planes) ----
  dim3 gm1(mb, HC / 64);
  k_gemm_mfma<128, 4, 0><<<gm1, 256, 0, stream>>>(x, w1t, xp1, as1, ad1, aS1, aD1,
                                                  nullptr, N, HC);
  k_coef<3><<<ab, 256, 0, stream>>>(rowptr, csrs, aS1, aD1, coef, N, ETp);
  dim3 ge1(ebk, 3);
  k_aggE<<<ge1, 256, 0, stream>>>(csrs, dstarr, coef, xp1, h1f, ET, ETp, 192, 192);
  // ---- layer 2: MFMA GEMM (A = h1f + bias + ELU fused) -> coef -> agg -> pool+final ----
  dim3 gm2(mb, LH / 64);
  k_gemm_mfma<192, 1, 1><<<gm2, 256, 0, stream>>>(h1f, w2t, xp2, as2, ad2, aS2, aD2,
                                                  b1, N, LH);
  k_coef<1><<<ab, 256, 0, stream>>>(rowptr, csrs, aS2, aD2, coef, N, ETp);
  dim3 ge2(ebk, 1);
  k_aggE<<<ge2, 256, 0, stream>>>(csrs, dstarr, coef, xp2, h2f, ET, ETp, 64, 64);
  k_poolfinal<<<GRAPHS, 256, 0, stream>>>(h2f, batch, b2, lw, lb, out, N);
}

// Round 22
// 400.689 us; speedup vs baseline: 1.6768x; 1.0174x over previous
//
#include <hip/hip_runtime.h>
#include <hip/hip_fp16.h>
#include <cstdint>

#define GRAPHS 128

using half8 = __attribute__((ext_vector_type(8))) _Float16;
using f32x4 = __attribute__((ext_vector_type(4))) float;

__device__ __forceinline__ int lane_bcast_i(int v, int l) {
  return __builtin_amdgcn_readlane(v, l);
}
__device__ __forceinline__ float lane_bcast_f(float v, int l) {
  return __int_as_float(__builtin_amdgcn_readlane(__float_as_int(v), l));
}
__device__ __forceinline__ void load_lds16(const __half* g, __half* l) {
  __builtin_amdgcn_global_load_lds(
      (const __attribute__((address_space(1))) void*)g,
      (__attribute__((address_space(3))) void*)l, 16, 0, 0);
}
#define WAIT_VM0 __builtin_amdgcn_s_waitcnt(0x0F70)  // vmcnt(0) only

// ---------------- prep A: degree histogram + weight transpose (merged, independent) ----------

__global__ __launch_bounds__(256) void k_degwt(
    const int* __restrict__ ei, int E, int ET, int* __restrict__ deg, int eb,
    const float* __restrict__ W1, __half* __restrict__ w1t,
    const float* __restrict__ W2, __half* __restrict__ w2t, int F, int HC, int LH) {
  int b = blockIdx.x;
  if (b < eb) {
    int e = b * 256 + threadIdx.x;
    if (e >= ET) return;
    int d = (e < E) ? ei[E + e] : (e - E);
    atomicAdd(&deg[d], 1);
    return;
  }
  int id = (b - eb) * 256 + threadIdx.x;
  if (id < F * HC) {
    int nn = id / F, kk = id % F;
    w1t[(size_t)nn * F + kk] = __float2half(W1[(size_t)kk * HC + nn]);
    return;
  }
  id -= F * HC;
  if (id < HC * LH) {
    int nn = id / HC, kk = id % HC;
    w2t[(size_t)nn * HC + kk] = __float2half(W2[(size_t)kk * LH + nn]);
  }
}

__global__ __launch_bounds__(256) void k_s1(const int* __restrict__ deg, int N,
                                            int* __restrict__ bsum) {
  int b = blockIdx.x, tid = threadIdx.x;
  int i0 = b * 1024 + tid * 4;
  int s = 0;
#pragma unroll
  for (int e = 0; e < 4; ++e) { int i = i0 + e; if (i < N) s += deg[i]; }
#pragma unroll
  for (int o = 32; o; o >>= 1) s += __shfl_xor(s, o);
  __shared__ int wt[4];
  int lane = tid & 63, wid = tid >> 6;
  if (lane == 0) wt[wid] = s;
  __syncthreads();
  if (tid == 0) bsum[b] = wt[0] + wt[1] + wt[2] + wt[3];
}

// s3 with self-computed block prefix (k_s2 eliminated; nb small)
__global__ __launch_bounds__(256) void k_s3(int* __restrict__ deg_cursor,
                                            const int* __restrict__ bsum,
                                            int* __restrict__ rowptr, int N) {
  int b = blockIdx.x, tid = threadIdx.x;
  int lane = tid & 63, wid = tid >> 6;
  __shared__ int spre;
  if (tid == 0) {
    int run = 0;
    for (int i = 0; i < b; ++i) run += bsum[i];
    spre = run;
  }
  int i0 = b * 1024 + tid * 4;
  int d[4];
#pragma unroll
  for (int e = 0; e < 4; ++e) { int i = i0 + e; d[e] = (i < N) ? deg_cursor[i] : 0; }
  int p0 = d[0], p1 = p0 + d[1], p2 = p1 + d[2], p3 = p2 + d[3];
  int incl = p3;
#pragma unroll
  for (int o = 1; o < 64; o <<= 1) { int u = __shfl_up(incl, o); if (lane >= o) incl += u; }
  __shared__ int wt[4];
  if (lane == 63) wt[wid] = incl;
  __syncthreads();
  int woff = 0;
  for (int w = 0; w < wid; ++w) woff += wt[w];
  int ex = spre + woff + incl - p3;
  int pre[4] = {0, p0, p1, p2};
#pragma unroll
  for (int e = 0; e < 4; ++e) {
    int i = i0 + e;
    if (i < N) { int st = ex + pre[e]; deg_cursor[i] = st; rowptr[i + 1] = st + d[e]; }
  }
  if (b == 0 && tid == 0) rowptr[0] = 0;
}

__global__ __launch_bounds__(256) void k_scatter(const int* __restrict__ ei, int E, int ET,
                                                 int* __restrict__ cursor,
                                                 int* __restrict__ csrs,
                                                 int* __restrict__ dstarr) {
  int e = blockIdx.x * 256 + threadIdx.x;
  if (e >= ET) return;
  int s, d;
  if (e < E) { s = ei[e]; d = ei[E + e]; } else { s = d = e - E; }
  int pos = atomicAdd(&cursor[d], 1);
  csrs[pos] = s;
  dstarr[pos] = d;
}

// ---------------- MFMA GEMM, LDS-tiled, fp32 A staged with inline cvt ----------------
// MODE 0: A = raw fp32 (x).  MODE 1: A = fp32 accumulators + bias + ELU (h1f).

template <int KT, int ASTR, int MODE>
__global__ __launch_bounds__(256) void k_gemm_mfma(
    const float* __restrict__ Af, const __half* __restrict__ Bth,
    __half* __restrict__ C, const float* __restrict__ attS, const float* __restrict__ attD,
    float* __restrict__ aS, float* __restrict__ aD, const float* __restrict__ bias,
    int M, int NC) {
  constexpr int K8 = KT / 8;
  constexpr int KS = KT / 32;
  __shared__ __align__(16) _Float16 Asm[64 * KT];
  __shared__ float sS[64][4], sD[64][4];
  int tid = threadIdx.x;
  int w = tid >> 6, lane = tid & 63;
  int col = lane & 15, quad = lane >> 4;
  int m0 = blockIdx.x * 64;
  int nblk = blockIdx.y * 64;
  int head = blockIdx.y;
  half8* As8 = (half8*)Asm;
  for (int i = tid; i < 64 * K8; i += 256) {
    int row = i / K8, c8 = i % K8;
    int gm = min(m0 + row, M - 1);
    const float* src = Af + (size_t)gm * KT + c8 * 8;
    float4 v0 = *(const float4*)src;
    float4 v1 = *(const float4*)(src + 4);
    float o[8] = {v0.x, v0.y, v0.z, v0.w, v1.x, v1.y, v1.z, v1.w};
    if (MODE == 1) {
      int c = c8 * 8;
#pragma unroll
      for (int k = 0; k < 8; ++k) {
        float t = o[k] + bias[c + k];
        o[k] = t > 0.f ? t : __expf(t) - 1.f;
      }
    }
    half8 h;
#pragma unroll
    for (int k = 0; k < 8; ++k) h[k] = (_Float16)o[k];
    As8[i] = h;
  }
  __syncthreads();
  int n0w = nblk + w * 16;
  const half8* B8 = (const half8*)Bth;
  half8 bf[KS];
#pragma unroll
  for (int s = 0; s < KS; ++s) bf[s] = B8[(size_t)(n0w + col) * K8 + s * 4 + quad];
  float asv = attS[n0w + col], adv = attD[n0w + col];
  f32x4 accs[4];
#pragma unroll
  for (int i = 0; i < 4; ++i) {
    f32x4 acc = {0.f, 0.f, 0.f, 0.f};
#pragma unroll
    for (int s = 0; s < KS; ++s) {
      half8 a = *(const half8*)&Asm[(i * 16 + col) * KT + s * 32 + quad * 8];
      acc = __builtin_amdgcn_mfma_f32_16x16x32_f16(a, bf[s], acc, 0, 0, 0);
    }
    accs[i] = acc;
#pragma unroll
    for (int r = 0; r < 4; ++r) {
      float sv = acc[r] * asv, dv = acc[r] * adv;
#pragma unroll
      for (int o = 1; o < 16; o <<= 1) { sv += __shfl_xor(sv, o); dv += __shfl_xor(dv, o); }
      if (col == 0) {
        int ml = i * 16 + quad * 4 + r;
        sS[ml][w] = sv; sD[ml][w] = dv;
      }
    }
  }
  __syncthreads();
  if (tid < 64) {
    int m = m0 + tid;
    if (m < M) {
      aS[(size_t)m * ASTR + head] = sS[tid][0] + sS[tid][1] + sS[tid][2] + sS[tid][3];
      aD[(size_t)m * ASTR + head] = sD[tid][0] + sD[tid][1] + sD[tid][2] + sD[tid][3];
    }
  }
  _Float16* Cs = Asm;
#pragma unroll
  for (int i = 0; i < 4; ++i)
#pragma unroll
    for (int r = 0; r < 4; ++r)
      Cs[(i * 16 + quad * 4 + r) * 64 + w * 16 + col] = (_Float16)accs[i][r];
  __syncthreads();
  for (int i = tid; i < 64 * 8; i += 256) {
    int row = i >> 3, c8 = i & 7;
    int gm = m0 + row;
    if (gm < M)
      *(half8*)&C[(size_t)gm * NC + nblk + c8 * 8] = ((half8*)Cs)[row * 8 + c8];
  }
}

// ---------------- per-edge softmax coefs (fp16 out), aS gathered once (deg<=64 path) --------

template <int NH>
__global__ __launch_bounds__(256) void k_coef(
    const int* __restrict__ rowptr, const int* __restrict__ csrs,
    const float* __restrict__ aS, const float* __restrict__ aD,
    __half* __restrict__ coef, int N, int ETp) {
  constexpr int ASTR = (NH == 3) ? 4 : 1;
  int wv = (blockIdx.x * 256 + (int)threadIdx.x) >> 6;
  if (wv >= N) return;
  int lane = threadIdx.x & 63;
  int start = rowptr[wv], end = rowptr[wv + 1];
  float ad[NH], m[NH], s[NH], al[NH];
#pragma unroll
  for (int h = 0; h < NH; ++h) {
    ad[h] = aD[(size_t)wv * ASTR + h];
    m[h] = -1e30f; s[h] = 0.f; al[h] = 0.f;
  }
  int j0 = start + lane;
  bool have = j0 < end;
  if (have) {
    int sb = csrs[j0];
    float av[NH];
    if (NH == 3) {
      float4 a4 = *(const float4*)&aS[(size_t)sb * 4];
      av[0] = a4.x; av[1] = a4.y; av[2] = a4.z;
    } else {
      av[0] = aS[sb];
    }
#pragma unroll
    for (int h = 0; h < NH; ++h) {
      float v = av[h] + ad[h];
      v = v > 0.f ? v : 0.2f * v;
      al[h] = v; m[h] = v; s[h] = 1.f;
    }
  }
  for (int jj = j0 + 64; jj < end; jj += 64) {   // degree > 64 (rare)
    int sb = csrs[jj];
    float av[NH];
    if (NH == 3) {
      float4 a4 = *(const float4*)&aS[(size_t)sb * 4];
      av[0] = a4.x; av[1] = a4.y; av[2] = a4.z;
    } else {
      av[0] = aS[sb];
    }
#pragma unroll
    for (int h = 0; h < NH; ++h) {
      float v = av[h] + ad[h];
      v = v > 0.f ? v : 0.2f * v;
      float M = fmaxf(m[h], v);
      s[h] = s[h] * __expf(m[h] - M) + __expf(v - M);
      m[h] = M;
    }
  }
#pragma unroll
  for (int h = 0; h < NH; ++h) {
    float mm = m[h], ss = s[h];
#pragma unroll
    for (int o = 1; o < 64; o <<= 1) {
      float om = __shfl_xor(mm, o), os = __shfl_xor(ss, o);
      float M = fmaxf(mm, om);
      ss = ss * __expf(mm - M) + os * __expf(om - M);
      mm = M;
    }
    m[h] = mm;
    s[h] = 1.0f / fmaxf(ss, 1e-16f);
  }
  if (have) {   // first 64 edges: reuse registers, no re-gather
#pragma unroll
    for (int h = 0; h < NH; ++h)
      coef[(size_t)h * ETp + j0] = __float2half(__expf(al[h] - m[h]) * s[h]);
  }
  for (int jj = j0 + 64; jj < end; jj += 64) {   // spillover re-gather (rare)
    int sb = csrs[jj];
    float av[NH];
    if (NH == 3) {
      float4 a4 = *(const float4*)&aS[(size_t)sb * 4];
      av[0] = a4.x; av[1] = a4.y; av[2] = a4.z;
    } else {
      av[0] = aS[sb];
    }
#pragma unroll
    for (int h = 0; h < NH; ++h) {
      float v = av[h] + ad[h];
      v = v > 0.f ? v : 0.2f * v;
      coef[(size_t)h * ETp + jj] = __float2half(__expf(v - m[h]) * s[h]);
    }
  }
}

// ---------------- edge-parallel aggregation: wave = 64 consecutive CSR edges ----------------

__global__ __launch_bounds__(256) void k_aggE(
    const int* __restrict__ csrs, const int* __restrict__ dstarr,
    const __half* __restrict__ coef, const __half* __restrict__ xp,
    float* __restrict__ outf, int ET, int ETp, int rowstr, int ostr) {
  __shared__ __half stage[4][4096];
  int wv = (blockIdx.x * 256 + (int)threadIdx.x) >> 6;
  int lane = threadIdx.x & 63;
  int wid = (threadIdx.x >> 6) & 3;
  __half* st = stage[wid];
  int head = blockIdx.y;
  int coloff = head * 64;
  int e0 = wv * 64;
  if (e0 >= ET) return;
  int j = e0 + lane;
  int jc = min(j, ET - 1);
  int sreg = csrs[jc];                          // coalesced
  int dstv = dstarr[jc];                        // coalesced
  float dd = (j < ET) ? __half2float(coef[(size_t)head * ETp + j]) : 0.f;  // coalesced
#pragma unroll
  for (int k = 0; k < 8; ++k) {
    int src = __shfl(sreg, k * 8 + (lane >> 3));
    const __half* g = xp + (size_t)src * rowstr + coloff + (lane & 7) * 8;
    load_lds16(g, st + k * 512);                // 8 rows of 64 halves per DMA
  }
  int dn = __shfl_down(dstv, 1);
  unsigned long long bmask = __ballot(lane == 63 || dn != dstv);  // segment-end lanes
  WAIT_VM0;                                     // the only wait in the wave's lifetime
  float acc = 0.f;
  int dcur = lane_bcast_i(dstv, 0);
#pragma unroll 4
  for (int u = 0; u < 64; ++u) {
    float c = lane_bcast_f(dd, u);
    acc = fmaf(c, __half2float(st[(u >> 3) * 512 + (u & 7) * 64 + lane]), acc);
    if ((bmask >> u) & 1ull) {                  // wave-uniform scalar test
      atomicAdd(&outf[(size_t)dcur * ostr + coloff + lane], acc);
      acc = 0.f;
      if (u < 63) dcur = lane_bcast_i(dstv, u + 1);
    }
  }
}

// ---------------- fused pooling + final linear (one block per graph, NO atomics) ------------

__global__ __launch_bounds__(256) void k_poolfinal(
    const float* __restrict__ h2f, const int* __restrict__ batch,
    const float* __restrict__ b2, const float* __restrict__ lw,
    const float* __restrict__ lb, float* __restrict__ out, int N) {
  int g = blockIdx.x;
  __shared__ int sse[2];
  __shared__ float red[4][64];
  if (threadIdx.x < 2) {
    int target = g + (int)threadIdx.x;
    int lo = 0, hi = N;
    while (lo < hi) { int mid = (lo + hi) >> 1; if (batch[mid] < target) lo = mid + 1; else hi = mid; }
    sse[threadIdx.x] = lo;
  }
  __syncthreads();
  int start = sse[0], end = sse[1];
  int lane = threadIdx.x & 63, wid = threadIdx.x >> 6;
  float acc = 0.f;
  for (int n = start + wid; n < end; n += 4) acc += h2f[(size_t)n * 64 + lane];
  red[wid][lane] = acc;
  __syncthreads();
  if (wid == 0) {
    float inv = 1.0f / fmaxf((float)(end - start), 1.0f);
    float pv = (red[0][lane] + red[1][lane] + red[2][lane] + red[3][lane]) * inv + b2[lane];
#pragma unroll
    for (int k = 0; k < 10; ++k) {
      float v = pv * lw[lane * 10 + k];
#pragma unroll
      for (int o = 1; o < 64; o <<= 1) v += __shfl_xor(v, o);
      if (lane == 0) out[g * 10 + k] = v + lb[k];
    }
  }
}

extern "C" void kernel_launch(void* const* d_in, const int* in_sizes, int n_in,
                              void* d_out, int out_size, void* d_ws, size_t ws_size,
                              hipStream_t stream) {
  const float* x = (const float*)d_in[0];
  const int* ei = (const int*)d_in[1];
  const int* batch = (const int*)d_in[2];
  const float* W1 = (const float*)d_in[3];
  const float* as1 = (const float*)d_in[4];
  const float* ad1 = (const float*)d_in[5];
  const float* b1 = (const float*)d_in[6];
  const float* W2 = (const float*)d_in[7];
  const float* as2 = (const float*)d_in[8];
  const float* ad2 = (const float*)d_in[9];
  const float* b2 = (const float*)d_in[10];
  const float* lw = (const float*)d_in[11];
  const float* lb = (const float*)d_in[12];
  float* out = (float*)d_out;

  const int N = in_sizes[2];        // 50000
  const int E = in_sizes[1] / 2;    // 800000
  const int ET = E + N;             // + self loops
  const int F = in_sizes[0] / N;    // 128
  const int HC = in_sizes[6];       // 192
  const int LH = in_sizes[10];      // 64
  const int ETp = (ET + 255) & ~255;

  size_t off = 0;
  auto alo = [&](size_t bytes) -> char* {
    char* p = (char*)d_ws + off;
    off += (bytes + 255) & ~(size_t)255;
    return p;
  };
  int* cursor = (int*)alo((size_t)N * 4);
  float* h1f = (float*)alo((size_t)N * 192 * 4);    // fp32 edge-flush accumulators
  float* h2f = (float*)alo((size_t)N * 64 * 4);
  size_t zbytes = off;                              // zero everything above
  float* aS1 = (float*)alo((size_t)N * 4 * 4);      // direct-stored by GEMM
  float* aD1 = (float*)alo((size_t)N * 4 * 4);
  float* aS2 = (float*)alo((size_t)N * 4);
  float* aD2 = (float*)alo((size_t)N * 4);
  int* rowptr = (int*)alo(((size_t)N + 1) * 4);
  int* csrs = (int*)alo((size_t)ET * 4);
  int* dstarr = (int*)alo((size_t)ET * 4);
  int* bsum = (int*)alo(64 * 4);
  __half* coef = (__half*)alo((size_t)3 * ETp * 2); // planar [head][dst-pos], fp16
  __half* w1t = (__half*)alo((size_t)HC * F * 2);
  __half* w2t = (__half*)alo((size_t)LH * HC * 2);
  __half* xp1 = (__half*)alo((size_t)N * 192 * 2 + 512);  // +pad: DMA clamp overreach
  __half* xp2 = (__half*)alo((size_t)N * 64 * 2 + 512);

  hipMemsetAsync(d_ws, 0, zbytes, stream);
  int eb = (ET + 255) / 256;
  int wtTot = F * HC + HC * LH;
  int wtb = (wtTot + 255) / 256;
  k_degwt<<<eb + wtb, 256, 0, stream>>>(ei, E, ET, cursor, eb, W1, w1t, W2, w2t, F, HC, LH);
  int nb = (N + 1023) / 1024;
  k_s1<<<nb, 256, 0, stream>>>(cursor, N, bsum);
  k_s3<<<nb, 256, 0, stream>>>(cursor, bsum, rowptr, N);
  k_scatter<<<eb, 256, 0, stream>>>(ei, E, ET, cursor, csrs, dstarr);

  int mb = (N + 63) / 64;
  int ab = (N + 3) / 4;
  int ewaves = (ET + 63) / 64;
  int ebk = (ewaves + 3) / 4;

  // ---- layer 1: MFMA GEMM (fp32 A inline-cvt) -> coef -> edge-parallel agg (3 planes) ----
  dim3 gm1(mb, HC / 64);
  k_gemm_mfma<128, 4, 0><<<gm1, 256, 0, stream>>>(x, w1t, xp1, as1, ad1, aS1, aD1,
                                                  nullptr, N, HC);
  k_coef<3><<<ab, 256, 0, stream>>>(rowptr, csrs, aS1, aD1, coef, N, ETp);
  dim3 ge1(ebk, 3);
  k_aggE<<<ge1, 256, 0, stream>>>(csrs, dstarr, coef, xp1, h1f, ET, ETp, 192, 192);
  // ---- layer 2: MFMA GEMM (A = h1f + bias + ELU fused) -> coef -> agg -> pool+final ----
  dim3 gm2(mb, LH / 64);
  k_gemm_mfma<192, 1, 1><<<gm2, 256, 0, stream>>>(h1f, w2t, xp2, as2, ad2, aS2, aD2,
                                                  b1, N, LH);
  k_coef<1><<<ab, 256, 0, stream>>>(rowptr, csrs, aS2, aD2, coef, N, ETp);
  dim3 ge2(ebk, 1);
  k_aggE<<<ge2, 256, 0, stream>>>(csrs, dstarr, coef, xp2, h2f, ET, ETp, 64, 64);
  k_poolfinal<<<GRAPHS, 256, 0, stream>>>(h2f, batch, b2, lw, lb, out, N);
}

// Round 23
// 384.193 us; speedup vs baseline: 1.7488x; 1.0429x over previous
//
#include <hip/hip_runtime.h>
#include <hip/hip_fp16.h>
#include <cstdint>

#define GRAPHS 128

using half8 = __attribute__((ext_vector_type(8))) _Float16;
using f32x4 = __attribute__((ext_vector_type(4))) float;

__device__ __forceinline__ int lane_bcast_i(int v, int l) {
  return __builtin_amdgcn_readlane(v, l);
}
__device__ __forceinline__ float lane_bcast_f(float v, int l) {
  return __int_as_float(__builtin_amdgcn_readlane(__float_as_int(v), l));
}
__device__ __forceinline__ void load_lds16(const __half* g, __half* l) {
  __builtin_amdgcn_global_load_lds(
      (const __attribute__((address_space(1))) void*)g,
      (__attribute__((address_space(3))) void*)l, 16, 0, 0);
}
#define WAIT_VM0 __builtin_amdgcn_s_waitcnt(0x0F70)  // vmcnt(0) only

// ---------------- prep A: degree histogram + weight transpose (merged, independent) ----------

__global__ __launch_bounds__(256) void k_degwt(
    const int* __restrict__ ei, int E, int ET, int* __restrict__ deg, int eb,
    const float* __restrict__ W1, __half* __restrict__ w1t,
    const float* __restrict__ W2, __half* __restrict__ w2t, int F, int HC, int LH) {
  int b = blockIdx.x;
  if (b < eb) {
    int e = b * 256 + threadIdx.x;
    if (e >= ET) return;
    int d = (e < E) ? ei[E + e] : (e - E);
    atomicAdd(&deg[d], 1);
    return;
  }
  int id = (b - eb) * 256 + threadIdx.x;
  if (id < F * HC) {
    int nn = id / F, kk = id % F;
    w1t[(size_t)nn * F + kk] = __float2half(W1[(size_t)kk * HC + nn]);
    return;
  }
  id -= F * HC;
  if (id < HC * LH) {
    int nn = id / HC, kk = id % HC;
    w2t[(size_t)nn * HC + kk] = __float2half(W2[(size_t)kk * LH + nn]);
  }
}

__global__ __launch_bounds__(256) void k_s1(const int* __restrict__ deg, int N,
                                            int* __restrict__ bsum) {
  int b = blockIdx.x, tid = threadIdx.x;
  int i0 = b * 1024 + tid * 4;
  int s = 0;
#pragma unroll
  for (int e = 0; e < 4; ++e) { int i = i0 + e; if (i < N) s += deg[i]; }
#pragma unroll
  for (int o = 32; o; o >>= 1) s += __shfl_xor(s, o);
  __shared__ int wt[4];
  int lane = tid & 63, wid = tid >> 6;
  if (lane == 0) wt[wid] = s;
  __syncthreads();
  if (tid == 0) bsum[b] = wt[0] + wt[1] + wt[2] + wt[3];
}

// s3 with self-computed block prefix
__global__ __launch_bounds__(256) void k_s3(int* __restrict__ deg_cursor,
                                            const int* __restrict__ bsum,
                                            int* __restrict__ rowptr, int N) {
  int b = blockIdx.x, tid = threadIdx.x;
  int lane = tid & 63, wid = tid >> 6;
  __shared__ int spre;
  if (tid == 0) {
    int run = 0;
    for (int i = 0; i < b; ++i) run += bsum[i];
    spre = run;
  }
  int i0 = b * 1024 + tid * 4;
  int d[4];
#pragma unroll
  for (int e = 0; e < 4; ++e) { int i = i0 + e; d[e] = (i < N) ? deg_cursor[i] : 0; }
  int p0 = d[0], p1 = p0 + d[1], p2 = p1 + d[2], p3 = p2 + d[3];
  int incl = p3;
#pragma unroll
  for (int o = 1; o < 64; o <<= 1) { int u = __shfl_up(incl, o); if (lane >= o) incl += u; }
  __shared__ int wt[4];
  if (lane == 63) wt[wid] = incl;
  __syncthreads();
  int woff = 0;
  for (int w = 0; w < wid; ++w) woff += wt[w];
  int ex = spre + woff + incl - p3;
  int pre[4] = {0, p0, p1, p2};
#pragma unroll
  for (int e = 0; e < 4; ++e) {
    int i = i0 + e;
    if (i < N) { int st = ex + pre[e]; deg_cursor[i] = st; rowptr[i + 1] = st + d[e]; }
  }
  if (b == 0 && tid == 0) rowptr[0] = 0;
}

__global__ __launch_bounds__(256) void k_scatter(const int* __restrict__ ei, int E, int ET,
                                                 int* __restrict__ cursor,
                                                 int* __restrict__ csrs,
                                                 int* __restrict__ dstarr) {
  int e = blockIdx.x * 256 + threadIdx.x;
  if (e >= ET) return;
  int s, d;
  if (e < E) { s = ei[e]; d = ei[E + e]; } else { s = d = e - E; }
  int pos = atomicAdd(&cursor[d], 1);
  csrs[pos] = s;
  dstarr[pos] = d;
}

// ---------------- MFMA GEMM, LDS-tiled, fp32 A staged with inline cvt ----------------
// MODE 0: A = raw fp32 (x).
// MODE 1: A = unnormalized numerators (h1f) -> /denom + bias + ELU during staging.

template <int KT, int ASTR, int MODE>
__global__ __launch_bounds__(256) void k_gemm_mfma(
    const float* __restrict__ Af, const __half* __restrict__ Bth,
    __half* __restrict__ C, const float* __restrict__ attS, const float* __restrict__ attD,
    float* __restrict__ aS, float* __restrict__ aD, const float* __restrict__ bias,
    const float* __restrict__ dnm, int Ndn, int M, int NC) {
  constexpr int K8 = KT / 8;
  constexpr int KS = KT / 32;
  __shared__ __align__(16) _Float16 Asm[64 * KT];
  __shared__ float sS[64][4], sD[64][4];
  int tid = threadIdx.x;
  int w = tid >> 6, lane = tid & 63;
  int col = lane & 15, quad = lane >> 4;
  int m0 = blockIdx.x * 64;
  int nblk = blockIdx.y * 64;
  int head = blockIdx.y;
  half8* As8 = (half8*)Asm;
  for (int i = tid; i < 64 * K8; i += 256) {
    int row = i / K8, c8 = i % K8;
    int gm = min(m0 + row, M - 1);
    const float* src = Af + (size_t)gm * KT + c8 * 8;
    float4 v0 = *(const float4*)src;
    float4 v1 = *(const float4*)(src + 4);
    float o[8] = {v0.x, v0.y, v0.z, v0.w, v1.x, v1.y, v1.z, v1.w};
    if (MODE == 1) {
      int c = c8 * 8;
      float inv = 1.0f / fmaxf(dnm[(size_t)(c8 >> 3) * Ndn + gm], 1e-16f);
#pragma unroll
      for (int k = 0; k < 8; ++k) {
        float t = o[k] * inv + bias[c + k];
        o[k] = t > 0.f ? t : __expf(t) - 1.f;
      }
    }
    half8 h;
#pragma unroll
    for (int k = 0; k < 8; ++k) h[k] = (_Float16)o[k];
    As8[i] = h;
  }
  __syncthreads();
  int n0w = nblk + w * 16;
  const half8* B8 = (const half8*)Bth;
  half8 bf[KS];
#pragma unroll
  for (int s = 0; s < KS; ++s) bf[s] = B8[(size_t)(n0w + col) * K8 + s * 4 + quad];
  float asv = attS[n0w + col], adv = attD[n0w + col];
  f32x4 accs[4];
#pragma unroll
  for (int i = 0; i < 4; ++i) {
    f32x4 acc = {0.f, 0.f, 0.f, 0.f};
#pragma unroll
    for (int s = 0; s < KS; ++s) {
      half8 a = *(const half8*)&Asm[(i * 16 + col) * KT + s * 32 + quad * 8];
      acc = __builtin_amdgcn_mfma_f32_16x16x32_f16(a, bf[s], acc, 0, 0, 0);
    }
    accs[i] = acc;
#pragma unroll
    for (int r = 0; r < 4; ++r) {
      float sv = acc[r] * asv, dv = acc[r] * adv;
#pragma unroll
      for (int o = 1; o < 16; o <<= 1) { sv += __shfl_xor(sv, o); dv += __shfl_xor(dv, o); }
      if (col == 0) {
        int ml = i * 16 + quad * 4 + r;
        sS[ml][w] = sv; sD[ml][w] = dv;
      }
    }
  }
  __syncthreads();
  if (tid < 64) {
    int m = m0 + tid;
    if (m < M) {
      aS[(size_t)m * ASTR + head] = sS[tid][0] + sS[tid][1] + sS[tid][2] + sS[tid][3];
      aD[(size_t)m * ASTR + head] = sD[tid][0] + sD[tid][1] + sD[tid][2] + sD[tid][3];
    }
  }
  _Float16* Cs = Asm;
#pragma unroll
  for (int i = 0; i < 4; ++i)
#pragma unroll
    for (int r = 0; r < 4; ++r)
      Cs[(i * 16 + quad * 4 + r) * 64 + w * 16 + col] = (_Float16)accs[i][r];
  __syncthreads();
  for (int i = tid; i < 64 * 8; i += 256) {
    int row = i >> 3, c8 = i & 7;
    int gm = m0 + row;
    if (gm < M)
      *(half8*)&C[(size_t)gm * NC + nblk + c8 * 8] = ((half8*)Cs)[row * 8 + c8];
  }
}

// ---------------- edge-parallel unnormalized exp-alpha (replaces wave-per-node coef) --------
// Softmax shift-invariance: skip per-dst max (alpha bounded ~±2). Denominators accumulate
// in aggE; division deferred to consumers.

template <int NH>
__global__ __launch_bounds__(256) void k_alpha(
    const int* __restrict__ csrs, const int* __restrict__ dstarr,
    const float* __restrict__ aS, const float* __restrict__ aD,
    __half* __restrict__ coef, int ET, int ETp) {
  int j = blockIdx.x * 256 + threadIdx.x;
  if (j >= ET) return;
  int s = csrs[j];     // coalesced
  int d = dstarr[j];   // coalesced
  if (NH == 3) {
    float4 a4 = *(const float4*)&aS[(size_t)s * 4];   // random 16B gather (1 per edge)
    float4 b4 = *(const float4*)&aD[(size_t)d * 4];   // dst-sorted -> near-coalesced
    float al[3] = {a4.x + b4.x, a4.y + b4.y, a4.z + b4.z};
#pragma unroll
    for (int h = 0; h < 3; ++h) {
      float v = al[h] > 0.f ? al[h] : 0.2f * al[h];
      coef[(size_t)h * ETp + j] = __float2half(__expf(v));
    }
  } else {
    float v = aS[s] + aD[d];
    v = v > 0.f ? v : 0.2f * v;
    coef[j] = __float2half(__expf(v));
  }
}

// ---------------- edge-parallel aggregation + denominator accumulation ----------------

__global__ __launch_bounds__(256) void k_aggE(
    const int* __restrict__ csrs, const int* __restrict__ dstarr,
    const __half* __restrict__ coef, const __half* __restrict__ xp,
    float* __restrict__ outf, float* __restrict__ dnm,
    int ET, int ETp, int rowstr, int ostr, int Ndn) {
  __shared__ __half stage[4][4096];
  int wv = (blockIdx.x * 256 + (int)threadIdx.x) >> 6;
  int lane = threadIdx.x & 63;
  int wid = (threadIdx.x >> 6) & 3;
  __half* st = stage[wid];
  int head = blockIdx.y;
  int coloff = head * 64;
  int e0 = wv * 64;
  if (e0 >= ET) return;
  int j = e0 + lane;
  int jc = min(j, ET - 1);
  int sreg = csrs[jc];                          // coalesced
  int dstv = dstarr[jc];                        // coalesced
  float dd = (j < ET) ? __half2float(coef[(size_t)head * ETp + j]) : 0.f;  // coalesced
#pragma unroll
  for (int k = 0; k < 8; ++k) {
    int src = __shfl(sreg, k * 8 + (lane >> 3));
    const __half* g = xp + (size_t)src * rowstr + coloff + (lane & 7) * 8;
    load_lds16(g, st + k * 512);                // 8 rows of 64 halves per DMA
  }
  int dn = __shfl_down(dstv, 1);
  unsigned long long bmask = __ballot(lane == 63 || dn != dstv);  // segment-end lanes
  WAIT_VM0;                                     // the only wait in the wave's lifetime
  float acc = 0.f, dsum = 0.f;
  int dcur = lane_bcast_i(dstv, 0);
#pragma unroll 4
  for (int u = 0; u < 64; ++u) {
    float c = lane_bcast_f(dd, u);
    acc = fmaf(c, __half2float(st[(u >> 3) * 512 + (u & 7) * 64 + lane]), acc);
    dsum += c;
    if ((bmask >> u) & 1ull) {                  // wave-uniform scalar test
      atomicAdd(&outf[(size_t)dcur * ostr + coloff + lane], acc);
      if (lane == 0) atomicAdd(&dnm[(size_t)head * Ndn + dcur], dsum);
      acc = 0.f; dsum = 0.f;
      if (u < 63) dcur = lane_bcast_i(dstv, u + 1);
    }
  }
}

// ---------------- fused pooling + final linear (one block per graph, NO atomics) ------------

__global__ __launch_bounds__(256) void k_poolfinal(
    const float* __restrict__ h2f, const float* __restrict__ dnm2,
    const int* __restrict__ batch, const float* __restrict__ b2,
    const float* __restrict__ lw, const float* __restrict__ lb,
    float* __restrict__ out, int N) {
  int g = blockIdx.x;
  __shared__ int sse[2];
  __shared__ float red[4][64];
  if (threadIdx.x < 2) {
    int target = g + (int)threadIdx.x;
    int lo = 0, hi = N;
    while (lo < hi) { int mid = (lo + hi) >> 1; if (batch[mid] < target) lo = mid + 1; else hi = mid; }
    sse[threadIdx.x] = lo;
  }
  __syncthreads();
  int start = sse[0], end = sse[1];
  int lane = threadIdx.x & 63, wid = threadIdx.x >> 6;
  float acc = 0.f;
  for (int n = start + wid; n < end; n += 4) {
    float inv = 1.0f / fmaxf(dnm2[n], 1e-16f);
    acc = fmaf(h2f[(size_t)n * 64 + lane], inv, acc);
  }
  red[wid][lane] = acc;
  __syncthreads();
  if (wid == 0) {
    float inv = 1.0f / fmaxf((float)(end - start), 1.0f);
    float pv = (red[0][lane] + red[1][lane] + red[2][lane] + red[3][lane]) * inv + b2[lane];
#pragma unroll
    for (int k = 0; k < 10; ++k) {
      float v = pv * lw[lane * 10 + k];
#pragma unroll
      for (int o = 1; o < 64; o <<= 1) v += __shfl_xor(v, o);
      if (lane == 0) out[g * 10 + k] = v + lb[k];
    }
  }
}

extern "C" void kernel_launch(void* const* d_in, const int* in_sizes, int n_in,
                              void* d_out, int out_size, void* d_ws, size_t ws_size,
                              hipStream_t stream) {
  const float* x = (const float*)d_in[0];
  const int* ei = (const int*)d_in[1];
  const int* batch = (const int*)d_in[2];
  const float* W1 = (const float*)d_in[3];
  const float* as1 = (const float*)d_in[4];
  const float* ad1 = (const float*)d_in[5];
  const float* b1 = (const float*)d_in[6];
  const float* W2 = (const float*)d_in[7];
  const float* as2 = (const float*)d_in[8];
  const float* ad2 = (const float*)d_in[9];
  const float* b2 = (const float*)d_in[10];
  const float* lw = (const float*)d_in[11];
  const float* lb = (const float*)d_in[12];
  float* out = (float*)d_out;

  const int N = in_sizes[2];        // 50000
  const int E = in_sizes[1] / 2;    // 800000
  const int ET = E + N;             // + self loops
  const int F = in_sizes[0] / N;    // 128
  const int HC = in_sizes[6];       // 192
  const int LH = in_sizes[10];      // 64
  const int ETp = (ET + 255) & ~255;

  size_t off = 0;
  auto alo = [&](size_t bytes) -> char* {
    char* p = (char*)d_ws + off;
    off += (bytes + 255) & ~(size_t)255;
    return p;
  };
  int* cursor = (int*)alo((size_t)N * 4);
  float* h1f = (float*)alo((size_t)N * 192 * 4);    // fp32 unnormalized numerators
  float* h2f = (float*)alo((size_t)N * 64 * 4);
  float* dnm1 = (float*)alo((size_t)3 * N * 4);     // softmax denominators [head][node]
  float* dnm2 = (float*)alo((size_t)N * 4);
  size_t zbytes = off;                              // zero everything above
  float* aS1 = (float*)alo((size_t)N * 4 * 4);      // direct-stored by GEMM
  float* aD1 = (float*)alo((size_t)N * 4 * 4);
  float* aS2 = (float*)alo((size_t)N * 4);
  float* aD2 = (float*)alo((size_t)N * 4);
  int* rowptr = (int*)alo(((size_t)N + 1) * 4);
  int* csrs = (int*)alo((size_t)ET * 4);
  int* dstarr = (int*)alo((size_t)ET * 4);
  int* bsum = (int*)alo(64 * 4);
  __half* coef = (__half*)alo((size_t)3 * ETp * 2); // planar [head][dst-pos], fp16 exp(alpha)
  __half* w1t = (__half*)alo((size_t)HC * F * 2);
  __half* w2t = (__half*)alo((size_t)LH * HC * 2);
  __half* xp1 = (__half*)alo((size_t)N * 192 * 2 + 512);  // +pad: DMA clamp overreach
  __half* xp2 = (__half*)alo((size_t)N * 64 * 2 + 512);

  hipMemsetAsync(d_ws, 0, zbytes, stream);
  int eb = (ET + 255) / 256;
  int wtTot = F * HC + HC * LH;
  int wtb = (wtTot + 255) / 256;
  k_degwt<<<eb + wtb, 256, 0, stream>>>(ei, E, ET, cursor, eb, W1, w1t, W2, w2t, F, HC, LH);
  int nb = (N + 1023) / 1024;
  k_s1<<<nb, 256, 0, stream>>>(cursor, N, bsum);
  k_s3<<<nb, 256, 0, stream>>>(cursor, bsum, rowptr, N);
  k_scatter<<<eb, 256, 0, stream>>>(ei, E, ET, cursor, csrs, dstarr);

  int mb = (N + 63) / 64;
  int ewaves = (ET + 63) / 64;
  int ebk = (ewaves + 3) / 4;

  // ---- layer 1: MFMA GEMM -> exp-alpha (edge-parallel) -> agg (+denom) ----
  dim3 gm1(mb, HC / 64);
  k_gemm_mfma<128, 4, 0><<<gm1, 256, 0, stream>>>(x, w1t, xp1, as1, ad1, aS1, aD1,
                                                  nullptr, nullptr, 0, N, HC);
  k_alpha<3><<<eb, 256, 0, stream>>>(csrs, dstarr, aS1, aD1, coef, ET, ETp);
  dim3 ge1(ebk, 3);
  k_aggE<<<ge1, 256, 0, stream>>>(csrs, dstarr, coef, xp1, h1f, dnm1, ET, ETp, 192, 192, N);
  // ---- layer 2: MFMA GEMM (A = h1f/denom + bias + ELU) -> exp-alpha -> agg -> pool+final ---
  dim3 gm2(mb, LH / 64);
  k_gemm_mfma<192, 1, 1><<<gm2, 256, 0, stream>>>(h1f, w2t, xp2, as2, ad2, aS2, aD2,
                                                  b1, dnm1, N, N, LH);
  k_alpha<1><<<eb, 256, 0, stream>>>(csrs, dstarr, aS2, aD2, coef, ET, ETp);
  dim3 ge2(ebk, 1);
  k_aggE<<<ge2, 256, 0, stream>>>(csrs, dstarr, coef, xp2, h2f, dnm2, ET, ETp, 64, 64, N);
  k_poolfinal<<<GRAPHS, 256, 0, stream>>>(h2f, dnm2, batch, b2, lw, lb, out, N);
}

// Round 24
// 372.049 us; speedup vs baseline: 1.8059x; 1.0326x over previous
//
#include <hip/hip_runtime.h>
#include <hip/hip_fp16.h>
#include <cstdint>

#define GRAPHS 128

using half8 = __attribute__((ext_vector_type(8))) _Float16;
using f32x4 = __attribute__((ext_vector_type(4))) float;

__device__ __forceinline__ int lane_bcast_i(int v, int l) {
  return __builtin_amdgcn_readlane(v, l);
}
__device__ __forceinline__ float lane_bcast_f(float v, int l) {
  return __int_as_float(__builtin_amdgcn_readlane(__float_as_int(v), l));
}
__device__ __forceinline__ void load_lds16(const __half* g, __half* l) {
  __builtin_amdgcn_global_load_lds(
      (const __attribute__((address_space(1))) void*)g,
      (__attribute__((address_space(3))) void*)l, 16, 0, 0);
}
#define WAIT_VM0 __builtin_amdgcn_s_waitcnt(0x0F70)  // vmcnt(0) only

// ---------------- prep A: degree histogram + weight transpose (merged, independent) ----------

__global__ __launch_bounds__(256) void k_degwt(
    const int* __restrict__ ei, int E, int ET, int* __restrict__ deg, int eb,
    const float* __restrict__ W1, __half* __restrict__ w1t,
    const float* __restrict__ W2, __half* __restrict__ w2t, int F, int HC, int LH) {
  int b = blockIdx.x;
  if (b < eb) {
    int e = b * 256 + threadIdx.x;
    if (e >= ET) return;
    int d = (e < E) ? ei[E + e] : (e - E);
    atomicAdd(&deg[d], 1);
    return;
  }
  int id = (b - eb) * 256 + threadIdx.x;
  if (id < F * HC) {
    int nn = id / F, kk = id % F;
    w1t[(size_t)nn * F + kk] = __float2half(W1[(size_t)kk * HC + nn]);
    return;
  }
  id -= F * HC;
  if (id < HC * LH) {
    int nn = id / HC, kk = id % HC;
    w2t[(size_t)nn * HC + kk] = __float2half(W2[(size_t)kk * LH + nn]);
  }
}

__global__ __launch_bounds__(256) void k_s1(const int* __restrict__ deg, int N,
                                            int* __restrict__ bsum) {
  int b = blockIdx.x, tid = threadIdx.x;
  int i0 = b * 1024 + tid * 4;
  int s = 0;
#pragma unroll
  for (int e = 0; e < 4; ++e) { int i = i0 + e; if (i < N) s += deg[i]; }
#pragma unroll
  for (int o = 32; o; o >>= 1) s += __shfl_xor(s, o);
  __shared__ int wt[4];
  int lane = tid & 63, wid = tid >> 6;
  if (lane == 0) wt[wid] = s;
  __syncthreads();
  if (tid == 0) bsum[b] = wt[0] + wt[1] + wt[2] + wt[3];
}

// s3 with self-computed block prefix (turns degree counts into scatter cursors)
__global__ __launch_bounds__(256) void k_s3(int* __restrict__ deg_cursor,
                                            const int* __restrict__ bsum, int N) {
  int b = blockIdx.x, tid = threadIdx.x;
  int lane = tid & 63, wid = tid >> 6;
  __shared__ int spre;
  if (tid == 0) {
    int run = 0;
    for (int i = 0; i < b; ++i) run += bsum[i];
    spre = run;
  }
  int i0 = b * 1024 + tid * 4;
  int d[4];
#pragma unroll
  for (int e = 0; e < 4; ++e) { int i = i0 + e; d[e] = (i < N) ? deg_cursor[i] : 0; }
  int p0 = d[0], p1 = p0 + d[1], p2 = p1 + d[2], p3 = p2 + d[3];
  int incl = p3;
#pragma unroll
  for (int o = 1; o < 64; o <<= 1) { int u = __shfl_up(incl, o); if (lane >= o) incl += u; }
  __shared__ int wt[4];
  if (lane == 63) wt[wid] = incl;
  __syncthreads();
  int woff = 0;
  for (int w = 0; w < wid; ++w) woff += wt[w];
  int ex = spre + woff + incl - p3;
  int pre[4] = {0, p0, p1, p2};
#pragma unroll
  for (int e = 0; e < 4; ++e) {
    int i = i0 + e;
    if (i < N) deg_cursor[i] = ex + pre[e];
  }
}

__global__ __launch_bounds__(256) void k_scatter(const int* __restrict__ ei, int E, int ET,
                                                 int* __restrict__ cursor,
                                                 int* __restrict__ csrs,
                                                 int* __restrict__ dstarr) {
  int e = blockIdx.x * 256 + threadIdx.x;
  if (e >= ET) return;
  int s, d;
  if (e < E) { s = ei[e]; d = ei[E + e]; } else { s = d = e - E; }
  int pos = atomicAdd(&cursor[d], 1);
  csrs[pos] = s;
  dstarr[pos] = d;
}

// ---------------- MFMA GEMM, LDS-tiled, fp32 A staged with inline cvt ----------------
// MODE 0: A = raw fp32 (x).
// MODE 1: A = unnormalized numerators (h1f) -> /denom + bias + ELU during staging.

template <int KT, int ASTR, int MODE>
__global__ __launch_bounds__(256) void k_gemm_mfma(
    const float* __restrict__ Af, const __half* __restrict__ Bth,
    __half* __restrict__ C, const float* __restrict__ attS, const float* __restrict__ attD,
    float* __restrict__ aS, float* __restrict__ aD, const float* __restrict__ bias,
    const float* __restrict__ dnm, int Ndn, int M, int NC) {
  constexpr int K8 = KT / 8;
  constexpr int KS = KT / 32;
  __shared__ __align__(16) _Float16 Asm[64 * KT];
  __shared__ float sS[64][4], sD[64][4];
  int tid = threadIdx.x;
  int w = tid >> 6, lane = tid & 63;
  int col = lane & 15, quad = lane >> 4;
  int m0 = blockIdx.x * 64;
  int nblk = blockIdx.y * 64;
  int head = blockIdx.y;
  half8* As8 = (half8*)Asm;
  for (int i = tid; i < 64 * K8; i += 256) {
    int row = i / K8, c8 = i % K8;
    int gm = min(m0 + row, M - 1);
    const float* src = Af + (size_t)gm * KT + c8 * 8;
    float4 v0 = *(const float4*)src;
    float4 v1 = *(const float4*)(src + 4);
    float o[8] = {v0.x, v0.y, v0.z, v0.w, v1.x, v1.y, v1.z, v1.w};
    if (MODE == 1) {
      int c = c8 * 8;
      float inv = 1.0f / fmaxf(dnm[(size_t)(c8 >> 3) * Ndn + gm], 1e-16f);
#pragma unroll
      for (int k = 0; k < 8; ++k) {
        float t = o[k] * inv + bias[c + k];
        o[k] = t > 0.f ? t : __expf(t) - 1.f;
      }
    }
    half8 h;
#pragma unroll
    for (int k = 0; k < 8; ++k) h[k] = (_Float16)o[k];
    As8[i] = h;
  }
  __syncthreads();
  int n0w = nblk + w * 16;
  const half8* B8 = (const half8*)Bth;
  half8 bf[KS];
#pragma unroll
  for (int s = 0; s < KS; ++s) bf[s] = B8[(size_t)(n0w + col) * K8 + s * 4 + quad];
  float asv = attS[n0w + col], adv = attD[n0w + col];
  f32x4 accs[4];
#pragma unroll
  for (int i = 0; i < 4; ++i) {
    f32x4 acc = {0.f, 0.f, 0.f, 0.f};
#pragma unroll
    for (int s = 0; s < KS; ++s) {
      half8 a = *(const half8*)&Asm[(i * 16 + col) * KT + s * 32 + quad * 8];
      acc = __builtin_amdgcn_mfma_f32_16x16x32_f16(a, bf[s], acc, 0, 0, 0);
    }
    accs[i] = acc;
#pragma unroll
    for (int r = 0; r < 4; ++r) {
      float sv = acc[r] * asv, dv = acc[r] * adv;
#pragma unroll
      for (int o = 1; o < 16; o <<= 1) { sv += __shfl_xor(sv, o); dv += __shfl_xor(dv, o); }
      if (col == 0) {
        int ml = i * 16 + quad * 4 + r;
        sS[ml][w] = sv; sD[ml][w] = dv;
      }
    }
  }
  __syncthreads();
  if (tid < 64) {
    int m = m0 + tid;
    if (m < M) {
      aS[(size_t)m * ASTR + head] = sS[tid][0] + sS[tid][1] + sS[tid][2] + sS[tid][3];
      aD[(size_t)m * ASTR + head] = sD[tid][0] + sD[tid][1] + sD[tid][2] + sD[tid][3];
    }
  }
  _Float16* Cs = Asm;
#pragma unroll
  for (int i = 0; i < 4; ++i)
#pragma unroll
    for (int r = 0; r < 4; ++r)
      Cs[(i * 16 + quad * 4 + r) * 64 + w * 16 + col] = (_Float16)accs[i][r];
  __syncthreads();
  for (int i = tid; i < 64 * 8; i += 256) {
    int row = i >> 3, c8 = i & 7;
    int gm = m0 + row;
    if (gm < M)
      *(half8*)&C[(size_t)gm * NC + nblk + c8 * 8] = ((half8*)Cs)[row * 8 + c8];
  }
}

// ---------------- edge-parallel aggregation, INLINE exp-alpha + denominator ----------------
// Per lane: one random 16B aS[src] gather (L2-resident 800KB table) + near-coalesced aD[dst]
// read + leaky+exp, all overlapped with the 8 staging DMAs under the single vmcnt(0).

template <int NH>
__global__ __launch_bounds__(256) void k_aggE(
    const int* __restrict__ csrs, const int* __restrict__ dstarr,
    const float* __restrict__ aS, const float* __restrict__ aD,
    const __half* __restrict__ xp, float* __restrict__ outf, float* __restrict__ dnm,
    int ET, int rowstr, int ostr, int Ndn) {
  __shared__ __half stage[4][4096];
  int wv = (blockIdx.x * 256 + (int)threadIdx.x) >> 6;
  int lane = threadIdx.x & 63;
  int wid = (threadIdx.x >> 6) & 3;
  __half* st = stage[wid];
  int head = blockIdx.y;
  int coloff = head * 64;
  int e0 = wv * 64;
  if (e0 >= ET) return;
  int j = e0 + lane;
  int jc = min(j, ET - 1);
  int sreg = csrs[jc];                          // coalesced
  int dstv = dstarr[jc];                        // coalesced
  // inline alpha: issued before DMAs; same vmcnt(0) covers everything
  float dd = 0.f;
  if (NH == 3) {
    float4 a4 = *(const float4*)&aS[(size_t)sreg * 4];   // random 16B, L2-resident
    float4 b4 = *(const float4*)&aD[(size_t)dstv * 4];   // dst-sorted -> near-coalesced
    float v = (head == 0) ? (a4.x + b4.x) : ((head == 1) ? (a4.y + b4.y) : (a4.z + b4.z));
    v = v > 0.f ? v : 0.2f * v;
    dd = __expf(v);
  } else {
    float v = aS[sreg] + aD[dstv];
    v = v > 0.f ? v : 0.2f * v;
    dd = __expf(v);
  }
  if (j >= ET) dd = 0.f;
#pragma unroll
  for (int k = 0; k < 8; ++k) {
    int src = __shfl(sreg, k * 8 + (lane >> 3));
    const __half* g = xp + (size_t)src * rowstr + coloff + (lane & 7) * 8;
    load_lds16(g, st + k * 512);                // 8 rows of 64 halves per DMA
  }
  int dn = __shfl_down(dstv, 1);
  unsigned long long bmask = __ballot(lane == 63 || dn != dstv);  // segment-end lanes
  WAIT_VM0;                                     // the only wait in the wave's lifetime
  float acc = 0.f, dsum = 0.f;
  int dcur = lane_bcast_i(dstv, 0);
#pragma unroll 4
  for (int u = 0; u < 64; ++u) {
    float c = lane_bcast_f(dd, u);
    acc = fmaf(c, __half2float(st[(u >> 3) * 512 + (u & 7) * 64 + lane]), acc);
    dsum += c;
    if ((bmask >> u) & 1ull) {                  // wave-uniform scalar test
      atomicAdd(&outf[(size_t)dcur * ostr + coloff + lane], acc);
      if (lane == 0) atomicAdd(&dnm[(size_t)head * Ndn + dcur], dsum);
      acc = 0.f; dsum = 0.f;
      if (u < 63) dcur = lane_bcast_i(dstv, u + 1);
    }
  }
}

// ---------------- fused pooling + final linear (one block per graph, NO atomics) ------------

__global__ __launch_bounds__(256) void k_poolfinal(
    const float* __restrict__ h2f, const float* __restrict__ dnm2,
    const int* __restrict__ batch, const float* __restrict__ b2,
    const float* __restrict__ lw, const float* __restrict__ lb,
    float* __restrict__ out, int N) {
  int g = blockIdx.x;
  __shared__ int sse[2];
  __shared__ float red[4][64];
  if (threadIdx.x < 2) {
    int target = g + (int)threadIdx.x;
    int lo = 0, hi = N;
    while (lo < hi) { int mid = (lo + hi) >> 1; if (batch[mid] < target) lo = mid + 1; else hi = mid; }
    sse[threadIdx.x] = lo;
  }
  __syncthreads();
  int start = sse[0], end = sse[1];
  int lane = threadIdx.x & 63, wid = threadIdx.x >> 6;
  float acc = 0.f;
  for (int n = start + wid; n < end; n += 4) {
    float inv = 1.0f / fmaxf(dnm2[n], 1e-16f);
    acc = fmaf(h2f[(size_t)n * 64 + lane], inv, acc);
  }
  red[wid][lane] = acc;
  __syncthreads();
  if (wid == 0) {
    float inv = 1.0f / fmaxf((float)(end - start), 1.0f);
    float pv = (red[0][lane] + red[1][lane] + red[2][lane] + red[3][lane]) * inv + b2[lane];
#pragma unroll
    for (int k = 0; k < 10; ++k) {
      float v = pv * lw[lane * 10 + k];
#pragma unroll
      for (int o = 1; o < 64; o <<= 1) v += __shfl_xor(v, o);
      if (lane == 0) out[g * 10 + k] = v + lb[k];
    }
  }
}

extern "C" void kernel_launch(void* const* d_in, const int* in_sizes, int n_in,
                              void* d_out, int out_size, void* d_ws, size_t ws_size,
                              hipStream_t stream) {
  const float* x = (const float*)d_in[0];
  const int* ei = (const int*)d_in[1];
  const int* batch = (const int*)d_in[2];
  const float* W1 = (const float*)d_in[3];
  const float* as1 = (const float*)d_in[4];
  const float* ad1 = (const float*)d_in[5];
  const float* b1 = (const float*)d_in[6];
  const float* W2 = (const float*)d_in[7];
  const float* as2 = (const float*)d_in[8];
  const float* ad2 = (const float*)d_in[9];
  const float* b2 = (const float*)d_in[10];
  const float* lw = (const float*)d_in[11];
  const float* lb = (const float*)d_in[12];
  float* out = (float*)d_out;

  const int N = in_sizes[2];        // 50000
  const int E = in_sizes[1] / 2;    // 800000
  const int ET = E + N;             // + self loops
  const int F = in_sizes[0] / N;    // 128
  const int HC = in_sizes[6];       // 192
  const int LH = in_sizes[10];      // 64

  size_t off = 0;
  auto alo = [&](size_t bytes) -> char* {
    char* p = (char*)d_ws + off;
    off += (bytes + 255) & ~(size_t)255;
    return p;
  };
  int* cursor = (int*)alo((size_t)N * 4);
  float* h1f = (float*)alo((size_t)N * 192 * 4);    // fp32 unnormalized numerators
  float* h2f = (float*)alo((size_t)N * 64 * 4);
  float* dnm1 = (float*)alo((size_t)3 * N * 4);     // softmax denominators [head][node]
  float* dnm2 = (float*)alo((size_t)N * 4);
  size_t zbytes = off;                              // zero everything above
  float* aS1 = (float*)alo((size_t)N * 4 * 4);      // direct-stored by GEMM
  float* aD1 = (float*)alo((size_t)N * 4 * 4);
  float* aS2 = (float*)alo((size_t)N * 4);
  float* aD2 = (float*)alo((size_t)N * 4);
  int* csrs = (int*)alo((size_t)ET * 4);
  int* dstarr = (int*)alo((size_t)ET * 4);
  int* bsum = (int*)alo(64 * 4);
  __half* w1t = (__half*)alo((size_t)HC * F * 2);
  __half* w2t = (__half*)alo((size_t)LH * HC * 2);
  __half* xp1 = (__half*)alo((size_t)N * 192 * 2 + 512);  // +pad: DMA clamp overreach
  __half* xp2 = (__half*)alo((size_t)N * 64 * 2 + 512);

  hipMemsetAsync(d_ws, 0, zbytes, stream);
  int eb = (ET + 255) / 256;
  int wtTot = F * HC + HC * LH;
  int wtb = (wtTot + 255) / 256;
  k_degwt<<<eb + wtb, 256, 0, stream>>>(ei, E, ET, cursor, eb, W1, w1t, W2, w2t, F, HC, LH);
  int nb = (N + 1023) / 1024;
  k_s1<<<nb, 256, 0, stream>>>(cursor, N, bsum);
  k_s3<<<nb, 256, 0, stream>>>(cursor, bsum, N);
  k_scatter<<<eb, 256, 0, stream>>>(ei, E, ET, cursor, csrs, dstarr);

  int mb = (N + 63) / 64;
  int ewaves = (ET + 63) / 64;
  int ebk = (ewaves + 3) / 4;

  // ---- layer 1: MFMA GEMM -> edge-parallel agg (inline alpha + denom) ----
  dim3 gm1(mb, HC / 64);
  k_gemm_mfma<128, 4, 0><<<gm1, 256, 0, stream>>>(x, w1t, xp1, as1, ad1, aS1, aD1,
                                                  nullptr, nullptr, 0, N, HC);
  dim3 ge1(ebk, 3);
  k_aggE<3><<<ge1, 256, 0, stream>>>(csrs, dstarr, aS1, aD1, xp1, h1f, dnm1,
                                     ET, 192, 192, N);
  // ---- layer 2: MFMA GEMM (A = h1f/denom + bias + ELU) -> agg -> pool+final ----
  dim3 gm2(mb, LH / 64);
  k_gemm_mfma<192, 1, 1><<<gm2, 256, 0, stream>>>(h1f, w2t, xp2, as2, ad2, aS2, aD2,
                                                  b1, dnm1, N, N, LH);
  dim3 ge2(ebk, 1);
  k_aggE<1><<<ge2, 256, 0, stream>>>(csrs, dstarr, aS2, aD2, xp2, h2f, dnm2,
                                     ET, 64, 64, N);
  k_poolfinal<<<GRAPHS, 256, 0, stream>>>(h2f, dnm2, batch, b2, lw, lb, out, N);
}